// Round 1
// baseline (2067.182 us; speedup 1.0000x reference)
//
#include <hip/hip_runtime.h>

// ---------------------------------------------------------------------------
// GCN 3-layer forward. Layout of d_ws (needs ~123 MB):
//   [0)          dis: N floats (also used as deg accumulator)
//   [400128)     flag: 1 int  (edge dtype detect)
//   [1 MB)       e32: 2E int32 (packed edge_index)
//   [16 MB)      bufA: N*128 floats (xw scratch)
//   [68 MB)      bufB: N*128 floats (h scratch)
// ---------------------------------------------------------------------------

__global__ void zero_f(float* __restrict__ p, long long n) {
  long long i = (long long)blockIdx.x * blockDim.x + threadIdx.x;
  const long long stride = (long long)gridDim.x * blockDim.x;
  for (; i < n; i += stride) p[i] = 0.0f;
}

// Detect whether edge_index arrived as int64 (odd int32 words all zero).
__global__ void detect_i64(const int* __restrict__ ei, int* __restrict__ flag) {
  __shared__ int nonzero;
  if (threadIdx.x == 0) nonzero = 0;
  __syncthreads();
  int acc = 0;
#pragma unroll
  for (int it = 0; it < 8; ++it) {
    const int j = threadIdx.x + (it << 8);  // 0..2047 -> reads idx <= 4095, safe
    acc |= ei[2 * j + 1];
  }
  if (acc != 0) atomicOr(&nonzero, 1);
  __syncthreads();
  if (threadIdx.x == 0) flag[0] = (nonzero == 0) ? 1 : 0;
}

__global__ void convert_edges(const int* __restrict__ ei, int* __restrict__ out,
                              const int* __restrict__ flag, int n) {
  const int j = blockIdx.x * blockDim.x + threadIdx.x;
  if (j >= n) return;
  const int use64 = flag[0];
  out[j] = use64 ? ei[2 * j] : ei[j];
}

__global__ void deg_accum(const int* __restrict__ dst, const float* __restrict__ ew,
                          float* __restrict__ deg, int E) {
  const int e = blockIdx.x * blockDim.x + threadIdx.x;
  if (e < E) unsafeAtomicAdd(&deg[dst[e]], ew[e]);
}

__global__ void dis_kernel(float* __restrict__ deg_dis, int N) {
  const int i = blockIdx.x * blockDim.x + threadIdx.x;
  if (i < N) deg_dis[i] = rsqrtf(deg_dis[i] + 1.0f);
}

// C[N x M] = A[N x 128] @ B[128 x M].  64x64 block tile, 4x4 thread tile.
__global__ __launch_bounds__(256, 2)
void gemm_k128(const float* __restrict__ A, const float* __restrict__ B,
               float* __restrict__ C, int N, int M) {
  __shared__ float As[64][132];   // row-major, +4 pad
  __shared__ float Bs[128][64];   // k-major
  const int tid = threadIdx.x;
  const int row0 = blockIdx.x << 6;
  const int col0 = blockIdx.y << 6;

  {
    const int rbase = tid >> 5;      // 0..7
    const int k = (tid & 31) << 2;   // 0..124
#pragma unroll
    for (int it = 0; it < 8; ++it) {
      const int r = rbase + (it << 3);
      const int row = row0 + r;
      float4 v = make_float4(0.f, 0.f, 0.f, 0.f);
      if (row < N) v = *(const float4*)(A + (long long)row * 128 + k);
      *(float4*)&As[r][k] = v;
    }
  }
  {
    const int kbase = tid >> 4;      // 0..15
    const int c = (tid & 15) << 2;   // 0..60
#pragma unroll
    for (int it = 0; it < 8; ++it) {
      const int kk = kbase + (it << 4);
      *(float4*)&Bs[kk][c] = *(const float4*)(B + (long long)kk * M + col0 + c);
    }
  }
  __syncthreads();

  const int tx = tid & 15;
  const int ty = tid >> 4;
  float acc[4][4] = {{0.f}};
#pragma unroll 4
  for (int k = 0; k < 128; ++k) {
    const float4 b = *(const float4*)&Bs[k][tx << 2];
    const float a0 = As[(ty << 2) + 0][k];
    const float a1 = As[(ty << 2) + 1][k];
    const float a2 = As[(ty << 2) + 2][k];
    const float a3 = As[(ty << 2) + 3][k];
    acc[0][0] = fmaf(a0, b.x, acc[0][0]); acc[0][1] = fmaf(a0, b.y, acc[0][1]);
    acc[0][2] = fmaf(a0, b.z, acc[0][2]); acc[0][3] = fmaf(a0, b.w, acc[0][3]);
    acc[1][0] = fmaf(a1, b.x, acc[1][0]); acc[1][1] = fmaf(a1, b.y, acc[1][1]);
    acc[1][2] = fmaf(a1, b.z, acc[1][2]); acc[1][3] = fmaf(a1, b.w, acc[1][3]);
    acc[2][0] = fmaf(a2, b.x, acc[2][0]); acc[2][1] = fmaf(a2, b.y, acc[2][1]);
    acc[2][2] = fmaf(a2, b.z, acc[2][2]); acc[2][3] = fmaf(a2, b.w, acc[2][3]);
    acc[3][0] = fmaf(a3, b.x, acc[3][0]); acc[3][1] = fmaf(a3, b.y, acc[3][1]);
    acc[3][2] = fmaf(a3, b.z, acc[3][2]); acc[3][3] = fmaf(a3, b.w, acc[3][3]);
  }

#pragma unroll
  for (int i = 0; i < 4; ++i) {
    const int row = row0 + (ty << 2) + i;
    if (row < N)
      *(float4*)(C + (long long)row * M + col0 + (tx << 2)) =
          make_float4(acc[i][0], acc[i][1], acc[i][2], acc[i][3]);
  }
}

// acc[i][f] = dis[i]^2 * xw[i][f] + bias[f]   (self-loop term + bias pre-fill)
template <int M>
__global__ void prefill(float* __restrict__ acc, const float* __restrict__ xw,
                        const float* __restrict__ dis, const float* __restrict__ bias,
                        int N) {
  const long long idx = (long long)blockIdx.x * blockDim.x + threadIdx.x;
  const long long total = (long long)N * (M / 4);
  if (idx >= total) return;
  const int i = (int)(idx / (M / 4));
  const int f4 = (int)(idx % (M / 4));
  const float d = dis[i];
  const float dsq = d * d;
  const float4 xv = ((const float4*)xw)[idx];
  const float4 bv = ((const float4*)bias)[f4];
  float4 o;
  o.x = fmaf(dsq, xv.x, bv.x);
  o.y = fmaf(dsq, xv.y, bv.y);
  o.z = fmaf(dsq, xv.z, bv.z);
  o.w = fmaf(dsq, xv.w, bv.w);
  ((float4*)acc)[idx] = o;
}

// One 64-lane wave per edge: acc[dst] += norm * xw[src]
template <int M>
__global__ void scatter_edges(const int* __restrict__ src, const int* __restrict__ dst,
                              const float* __restrict__ ew, const float* __restrict__ dis,
                              const float* __restrict__ xw, float* __restrict__ acc,
                              int E) {
  const long long idx = (long long)blockIdx.x * blockDim.x + threadIdx.x;
  const int e = (int)(idx >> 6);
  const int lane = (int)(idx & 63);
  if (e >= E) return;
  const int s = src[e];
  const int d = dst[e];
  const float nrm = dis[s] * ew[e] * dis[d];
  const float* xr = xw + (long long)s * M;
  float* ar = acc + (long long)d * M;
#pragma unroll
  for (int f = lane; f < M; f += 64)
    unsafeAtomicAdd(&ar[f], nrm * xr[f]);
}

__global__ void relu_inplace(float* __restrict__ p, long long n4) {
  const long long idx = (long long)blockIdx.x * blockDim.x + threadIdx.x;
  if (idx >= n4) return;
  float4 v = ((float4*)p)[idx];
  v.x = fmaxf(v.x, 0.f);
  v.y = fmaxf(v.y, 0.f);
  v.z = fmaxf(v.z, 0.f);
  v.w = fmaxf(v.w, 0.f);
  ((float4*)p)[idx] = v;
}

extern "C" void kernel_launch(void* const* d_in, const int* in_sizes, int n_in,
                              void* d_out, int out_size, void* d_ws, size_t ws_size,
                              hipStream_t stream) {
  const float* x  = (const float*)d_in[0];
  const int*   ei = (const int*)d_in[1];
  const float* ew = (const float*)d_in[2];
  const float* W1 = (const float*)d_in[3];
  const float* b1 = (const float*)d_in[4];
  const float* W2 = (const float*)d_in[5];
  const float* b2 = (const float*)d_in[6];
  const float* W3 = (const float*)d_in[7];
  const float* b3 = (const float*)d_in[8];
  float* out = (float*)d_out;

  const int IN = 128, HID = 128;
  const int N = in_sizes[0] / IN;      // 100000
  const int E = in_sizes[2];           // 1600000
  (void)in_sizes[8];                   // OUT = 64 (template constant below)

  char* ws = (char*)d_ws;
  float* dis  = (float*)(ws);
  int*   flag = (int*)(ws + 400128);
  int*   e32  = (int*)(ws + (1u << 20));
  float* bufA = (float*)(ws + (16u << 20));
  float* bufB = (float*)(ws + (68u << 20));
  const int* src = e32;
  const int* dst = e32 + E;

  const dim3 blk(256);

  // --- edge index normalization + degree/dis ---
  hipLaunchKernelGGL(detect_i64, dim3(1), blk, 0, stream, ei, flag);
  const int n2 = 2 * E;
  hipLaunchKernelGGL(convert_edges, dim3((n2 + 255) / 256), blk, 0, stream, ei, e32, flag, n2);
  hipLaunchKernelGGL(zero_f, dim3(512), blk, 0, stream, dis, (long long)N);
  hipLaunchKernelGGL(deg_accum, dim3((E + 255) / 256), blk, 0, stream, dst, ew, dis, E);
  hipLaunchKernelGGL(dis_kernel, dim3((N + 255) / 256), blk, 0, stream, dis, N);

  const int gRows = (N + 63) / 64;
  const long long nh4 = (long long)N * (HID / 4);
  const long long sc128 = (long long)E * 64;

  // --- layer 1: h1 = relu(A_hat @ (x @ W1) + b1) ---
  hipLaunchKernelGGL(gemm_k128, dim3(gRows, HID / 64), blk, 0, stream, x, W1, bufA, N, HID);
  hipLaunchKernelGGL((prefill<128>), dim3((unsigned)((nh4 + 255) / 256)), blk, 0, stream,
                     bufB, bufA, dis, b1, N);
  hipLaunchKernelGGL((scatter_edges<128>), dim3((unsigned)((sc128 + 255) / 256)), blk, 0, stream,
                     src, dst, ew, dis, bufA, bufB, E);
  hipLaunchKernelGGL(relu_inplace, dim3((unsigned)((nh4 + 255) / 256)), blk, 0, stream, bufB, nh4);

  // --- layer 2: h2 = relu(A_hat @ (h1 @ W2) + b2) ---
  hipLaunchKernelGGL(gemm_k128, dim3(gRows, HID / 64), blk, 0, stream, bufB, W2, bufA, N, HID);
  hipLaunchKernelGGL((prefill<128>), dim3((unsigned)((nh4 + 255) / 256)), blk, 0, stream,
                     bufB, bufA, dis, b2, N);
  hipLaunchKernelGGL((scatter_edges<128>), dim3((unsigned)((sc128 + 255) / 256)), blk, 0, stream,
                     src, dst, ew, dis, bufA, bufB, E);
  hipLaunchKernelGGL(relu_inplace, dim3((unsigned)((nh4 + 255) / 256)), blk, 0, stream, bufB, nh4);

  // --- layer 3: out = A_hat @ (h2 @ W3) + b3 ---
  hipLaunchKernelGGL(gemm_k128, dim3(gRows, 1), blk, 0, stream, bufB, W3, bufA, N, 64);
  const long long no4 = (long long)N * (64 / 4);
  hipLaunchKernelGGL((prefill<64>), dim3((unsigned)((no4 + 255) / 256)), blk, 0, stream,
                     out, bufA, dis, b3, N);
  hipLaunchKernelGGL((scatter_edges<64>), dim3((unsigned)((sc128 + 255) / 256)), blk, 0, stream,
                     src, dst, ew, dis, bufA, out, E);
}

// Round 2
// 1201.090 us; speedup vs baseline: 1.7211x; 1.7211x over previous
//
#include <hip/hip_runtime.h>

// ---------------------------------------------------------------------------
// GCN 3-layer forward, CSR-gather version (no float atomics in hot path).
// d_ws layout (max 119.2 MB, proven safe in R1):
//   [0)        dis: N floats (deg accumulator, then rsqrt in place)
//   [512K)     flag: 1 int (edge dtype detect)
//   [1 MB)     row_start: (N+1) ints
//   [1.5 MB)   cursor: N ints (counts -> exclusive prefix -> fill cursor)
//   [2 MB)     csr: E x int2 {src, norm-as-int}  (12.8 MB)
//   [16 MB)    bufA: N*128 floats (xw scratch)
//   [68 MB)    bufB: N*128 floats (h scratch)
// ---------------------------------------------------------------------------

__global__ void zero_bytes(char* __restrict__ p, long long n) {
  long long i = (long long)blockIdx.x * blockDim.x + threadIdx.x;
  const long long stride = (long long)gridDim.x * blockDim.x;
  float* f = (float*)p;
  for (long long j = i; j < n / 4; j += stride) f[j] = 0.0f;
}

// Detect whether edge_index arrived as int64 (odd int32 words all zero).
__global__ void detect_i64(const int* __restrict__ ei, int* __restrict__ flag) {
  __shared__ int nonzero;
  if (threadIdx.x == 0) nonzero = 0;
  __syncthreads();
  int acc = 0;
#pragma unroll
  for (int it = 0; it < 8; ++it) {
    const int j = threadIdx.x + (it << 8);
    acc |= ei[2 * j + 1];
  }
  if (acc != 0) atomicOr(&nonzero, 1);
  __syncthreads();
  if (threadIdx.x == 0) flag[0] = (nonzero == 0) ? 1 : 0;
}

// counts[dst]++ and deg[dst] += ew, reading edge_index in either layout.
__global__ void count_deg(const int* __restrict__ ei, const int* __restrict__ flag,
                          const float* __restrict__ ew, int* __restrict__ counts,
                          float* __restrict__ deg, int E) {
  const int e = blockIdx.x * blockDim.x + threadIdx.x;
  if (e >= E) return;
  const int use64 = flag[0];
  const int d = use64 ? ei[2 * (E + e)] : ei[E + e];
  atomicAdd(&counts[d], 1);
  unsafeAtomicAdd(&deg[d], ew[e]);
}

// Single-block exclusive scan of counts (in `cursor`), N up to ~1M.
// Writes row_start[0..N] and leaves cursor[i] = row_start[i].
__global__ __launch_bounds__(1024)
void scan_counts(int* __restrict__ cursor, int* __restrict__ row_start, int N) {
  __shared__ int sums[1024];
  const int t = threadIdx.x;
  const int per = (N + 1023) / 1024;
  const int lo = t * per;
  const int hi = (lo + per < N) ? lo + per : N;
  int s = 0;
  for (int j = lo; j < hi; ++j) s += cursor[j];
  sums[t] = s;
  __syncthreads();
  for (int off = 1; off < 1024; off <<= 1) {
    const int add = (t >= off) ? sums[t - off] : 0;
    __syncthreads();
    sums[t] += add;
    __syncthreads();
  }
  int run = (t == 0) ? 0 : sums[t - 1];
  for (int j = lo; j < hi; ++j) {
    const int c = cursor[j];
    row_start[j] = run;
    cursor[j] = run;
    run += c;
  }
  if (t == 1023) row_start[N] = sums[1023];
}

__global__ void dis_kernel(float* __restrict__ deg_dis, int N) {
  const int i = blockIdx.x * blockDim.x + threadIdx.x;
  if (i < N) deg_dis[i] = rsqrtf(deg_dis[i] + 1.0f);
}

// csr[pos] = {src, norm} grouped by dst via cursor.
__global__ void fill_csr(const int* __restrict__ ei, const int* __restrict__ flag,
                         const float* __restrict__ ew, const float* __restrict__ dis,
                         int* __restrict__ cursor, int2* __restrict__ csr, int E) {
  const int e = blockIdx.x * blockDim.x + threadIdx.x;
  if (e >= E) return;
  const int use64 = flag[0];
  const int s = use64 ? ei[2 * e] : ei[e];
  const int d = use64 ? ei[2 * (E + e)] : ei[E + e];
  const float nm = dis[s] * ew[e] * dis[d];
  const int pos = atomicAdd(&cursor[d], 1);
  csr[pos] = make_int2(s, __float_as_int(nm));
}

// C[N x M] = A[N x 128] @ B[128 x M].  64x64 block tile, 4x4 thread tile.
__global__ __launch_bounds__(256, 2)
void gemm_k128(const float* __restrict__ A, const float* __restrict__ B,
               float* __restrict__ C, int N, int M) {
  __shared__ float As[64][132];
  __shared__ float Bs[128][64];
  const int tid = threadIdx.x;
  const int row0 = blockIdx.x << 6;
  const int col0 = blockIdx.y << 6;

  {
    const int rbase = tid >> 5;
    const int k = (tid & 31) << 2;
#pragma unroll
    for (int it = 0; it < 8; ++it) {
      const int r = rbase + (it << 3);
      const int row = row0 + r;
      float4 v = make_float4(0.f, 0.f, 0.f, 0.f);
      if (row < N) v = *(const float4*)(A + (long long)row * 128 + k);
      *(float4*)&As[r][k] = v;
    }
  }
  {
    const int kbase = tid >> 4;
    const int c = (tid & 15) << 2;
#pragma unroll
    for (int it = 0; it < 8; ++it) {
      const int kk = kbase + (it << 4);
      *(float4*)&Bs[kk][c] = *(const float4*)(B + (long long)kk * M + col0 + c);
    }
  }
  __syncthreads();

  const int tx = tid & 15;
  const int ty = tid >> 4;
  float acc[4][4] = {{0.f}};
#pragma unroll 4
  for (int k = 0; k < 128; ++k) {
    const float4 b = *(const float4*)&Bs[k][tx << 2];
    const float a0 = As[(ty << 2) + 0][k];
    const float a1 = As[(ty << 2) + 1][k];
    const float a2 = As[(ty << 2) + 2][k];
    const float a3 = As[(ty << 2) + 3][k];
    acc[0][0] = fmaf(a0, b.x, acc[0][0]); acc[0][1] = fmaf(a0, b.y, acc[0][1]);
    acc[0][2] = fmaf(a0, b.z, acc[0][2]); acc[0][3] = fmaf(a0, b.w, acc[0][3]);
    acc[1][0] = fmaf(a1, b.x, acc[1][0]); acc[1][1] = fmaf(a1, b.y, acc[1][1]);
    acc[1][2] = fmaf(a1, b.z, acc[1][2]); acc[1][3] = fmaf(a1, b.w, acc[1][3]);
    acc[2][0] = fmaf(a2, b.x, acc[2][0]); acc[2][1] = fmaf(a2, b.y, acc[2][1]);
    acc[2][2] = fmaf(a2, b.z, acc[2][2]); acc[2][3] = fmaf(a2, b.w, acc[2][3]);
    acc[3][0] = fmaf(a3, b.x, acc[3][0]); acc[3][1] = fmaf(a3, b.y, acc[3][1]);
    acc[3][2] = fmaf(a3, b.z, acc[3][2]); acc[3][3] = fmaf(a3, b.w, acc[3][3]);
  }

#pragma unroll
  for (int i = 0; i < 4; ++i) {
    const int row = row0 + (ty << 2) + i;
    if (row < N)
      *(float4*)(C + (long long)row * M + col0 + (tx << 2)) =
          make_float4(acc[i][0], acc[i][1], acc[i][2], acc[i][3]);
  }
}

// One wave per dst node: out[i] = (relu)(sum_e norm*xw[src] + dis_i^2*xw[i] + b)
template <int M, bool RELU>
__global__ __launch_bounds__(256)
void gather(const int2* __restrict__ csr, const int* __restrict__ row_start,
            const float* __restrict__ xw, const float* __restrict__ dis,
            const float* __restrict__ bias, float* __restrict__ out, int N) {
  const int node = (blockIdx.x << 2) + (threadIdx.x >> 6);
  const int lane = threadIdx.x & 63;
  if (node >= N) return;
  const int beg = row_start[node];
  const int end = row_start[node + 1];
  if (M == 128) {
    const int c = lane << 1;
    float2 acc = make_float2(0.f, 0.f);
    for (int e = beg; e < end; ++e) {
      const int2 p = csr[e];
      const float nm = __int_as_float(p.y);
      const float2 v = *(const float2*)(xw + (long long)p.x * 128 + c);
      acc.x = fmaf(nm, v.x, acc.x);
      acc.y = fmaf(nm, v.y, acc.y);
    }
    const float di = dis[node];
    const float dsq = di * di;
    const float2 sv = *(const float2*)(xw + (long long)node * 128 + c);
    const float2 bv = *(const float2*)(bias + c);
    acc.x = fmaf(dsq, sv.x, acc.x) + bv.x;
    acc.y = fmaf(dsq, sv.y, acc.y) + bv.y;
    if (RELU) { acc.x = fmaxf(acc.x, 0.f); acc.y = fmaxf(acc.y, 0.f); }
    *(float2*)(out + (long long)node * 128 + c) = acc;
  } else {
    float acc = 0.f;
    for (int e = beg; e < end; ++e) {
      const int2 p = csr[e];
      acc = fmaf(__int_as_float(p.y), xw[(long long)p.x * 64 + lane], acc);
    }
    const float di = dis[node];
    float r = fmaf(di * di, xw[(long long)node * 64 + lane], acc) + bias[lane];
    if (RELU) r = fmaxf(r, 0.f);
    out[(long long)node * 64 + lane] = r;
  }
}

extern "C" void kernel_launch(void* const* d_in, const int* in_sizes, int n_in,
                              void* d_out, int out_size, void* d_ws, size_t ws_size,
                              hipStream_t stream) {
  const float* x  = (const float*)d_in[0];
  const int*   ei = (const int*)d_in[1];
  const float* ew = (const float*)d_in[2];
  const float* W1 = (const float*)d_in[3];
  const float* b1 = (const float*)d_in[4];
  const float* W2 = (const float*)d_in[5];
  const float* b2 = (const float*)d_in[6];
  const float* W3 = (const float*)d_in[7];
  const float* b3 = (const float*)d_in[8];
  float* out = (float*)d_out;

  const int IN = 128, HID = 128;
  const int N = in_sizes[0] / IN;   // 100000
  const int E = in_sizes[2];        // 1600000

  char* ws = (char*)d_ws;
  float* dis       = (float*)(ws);
  int*   flag      = (int*)(ws + (512u << 10));
  int*   row_start = (int*)(ws + (1u << 20));
  int*   cursor    = (int*)(ws + (1u << 20) + (512u << 10));
  int2*  csr       = (int2*)(ws + (2u << 20));
  float* bufA      = (float*)(ws + (16u << 20));
  float* bufB      = (float*)(ws + (68u << 20));

  const dim3 blk(256);
  const int gE = (E + 255) / 256;
  const int gN = (N + 255) / 256;

  // --- CSR build + normalization coefficients ---
  hipLaunchKernelGGL(detect_i64, dim3(1), blk, 0, stream, ei, flag);
  hipLaunchKernelGGL(zero_bytes, dim3(256), blk, 0, stream, (char*)dis, (long long)N * 4);
  hipLaunchKernelGGL(zero_bytes, dim3(256), blk, 0, stream, (char*)cursor, (long long)N * 4);
  hipLaunchKernelGGL(count_deg, dim3(gE), blk, 0, stream, ei, flag, ew, cursor, dis, E);
  hipLaunchKernelGGL(scan_counts, dim3(1), dim3(1024), 0, stream, cursor, row_start, N);
  hipLaunchKernelGGL(dis_kernel, dim3(gN), blk, 0, stream, dis, N);
  hipLaunchKernelGGL(fill_csr, dim3(gE), blk, 0, stream, ei, flag, ew, dis, cursor, csr, E);

  const int gRows = (N + 63) / 64;
  const int gGather = (N + 3) / 4;

  // --- layer 1 ---
  hipLaunchKernelGGL(gemm_k128, dim3(gRows, HID / 64), blk, 0, stream, x, W1, bufA, N, HID);
  hipLaunchKernelGGL((gather<128, true>), dim3(gGather), blk, 0, stream,
                     csr, row_start, bufA, dis, b1, bufB, N);
  // --- layer 2 ---
  hipLaunchKernelGGL(gemm_k128, dim3(gRows, HID / 64), blk, 0, stream, bufB, W2, bufA, N, HID);
  hipLaunchKernelGGL((gather<128, true>), dim3(gGather), blk, 0, stream,
                     csr, row_start, bufA, dis, b2, bufB, N);
  // --- layer 3 ---
  hipLaunchKernelGGL(gemm_k128, dim3(gRows, 1), blk, 0, stream, bufB, W3, bufA, N, 64);
  hipLaunchKernelGGL((gather<64, false>), dim3(gGather), blk, 0, stream,
                     csr, row_start, bufA, dis, b3, out, N);
}

// Round 3
// 809.532 us; speedup vs baseline: 2.5536x; 1.4837x over previous
//
#include <hip/hip_runtime.h>

// ---------------------------------------------------------------------------
// GCN 3-layer forward, CSR-gather, parallel 3-phase scan.
// d_ws layout (max ~119.2 MB):
//   [0)        dis: N floats (deg accumulator, then rsqrt in place)
//   [512K)     flag: 1 int (edge dtype detect)
//   [768K)     bsums: up to 1024 ints (scan block partials)
//   [1 MB)     row_start: (N+1) ints
//   [1.5 MB)   cursor: N ints (counts -> fill cursor)
//   [2 MB)     csr: E x int2 {src, norm-as-int}  (12.8 MB)
//   [16 MB)    bufA: N*128 floats (xw scratch)
//   [68 MB)    bufB: N*128 floats (h scratch)
// ---------------------------------------------------------------------------

__global__ void zero_ints(int* __restrict__ p, int n) {
  int i = blockIdx.x * blockDim.x + threadIdx.x;
  const int stride = gridDim.x * blockDim.x;
  for (; i < n; i += stride) p[i] = 0;
}

// Detect whether edge_index arrived as int64 (odd int32 words all zero).
__global__ void detect_i64(const int* __restrict__ ei, int* __restrict__ flag) {
  __shared__ int nonzero;
  if (threadIdx.x == 0) nonzero = 0;
  __syncthreads();
  int acc = 0;
#pragma unroll
  for (int it = 0; it < 8; ++it) {
    const int j = threadIdx.x + (it << 8);
    acc |= ei[2 * j + 1];
  }
  if (acc != 0) atomicOr(&nonzero, 1);
  __syncthreads();
  if (threadIdx.x == 0) flag[0] = (nonzero == 0) ? 1 : 0;
}

// counts[dst]++ and deg[dst] += ew, reading edge_index in either layout.
__global__ void count_deg(const int* __restrict__ ei, const int* __restrict__ flag,
                          const float* __restrict__ ew, int* __restrict__ counts,
                          float* __restrict__ deg, int E) {
  const int e = blockIdx.x * blockDim.x + threadIdx.x;
  if (e >= E) return;
  const int use64 = flag[0];
  const int d = use64 ? ei[2 * (E + e)] : ei[E + e];
  atomicAdd(&counts[d], 1);
  unsafeAtomicAdd(&deg[d], ew[e]);
}

// ---- 3-phase device-wide exclusive scan (chunk = 1024 elems/block) ----
__global__ __launch_bounds__(256)
void scan_phase1(const int* __restrict__ counts, int* __restrict__ bsums, int N) {
  __shared__ int red[256];
  const int t = threadIdx.x;
  const int base = blockIdx.x * 1024 + t * 4;
  int s = 0;
#pragma unroll
  for (int j = 0; j < 4; ++j) {
    const int idx = base + j;
    if (idx < N) s += counts[idx];
  }
  red[t] = s;
  __syncthreads();
  for (int off = 128; off > 0; off >>= 1) {
    if (t < off) red[t] += red[t + off];
    __syncthreads();
  }
  if (t == 0) bsums[blockIdx.x] = red[0];
}

__global__ __launch_bounds__(1024)
void scan_phase2(int* __restrict__ bsums, int* __restrict__ row_start, int B, int N) {
  __shared__ int s[1024];
  const int t = threadIdx.x;
  const int v = (t < B) ? bsums[t] : 0;
  s[t] = v;
  __syncthreads();
  for (int off = 1; off < 1024; off <<= 1) {
    const int add = (t >= off) ? s[t - off] : 0;
    __syncthreads();
    s[t] += add;
    __syncthreads();
  }
  if (t < B) bsums[t] = s[t] - v;           // exclusive prefix of block sums
  if (t == B - 1) row_start[N] = s[t];      // total
}

__global__ __launch_bounds__(256)
void scan_phase3(const int* __restrict__ counts, const int* __restrict__ bsums,
                 int* __restrict__ row_start, int* __restrict__ cursor, int N) {
  __shared__ int tsum[256];
  const int t = threadIdx.x;
  const int base = blockIdx.x * 1024 + t * 4;
  int v[4];
#pragma unroll
  for (int j = 0; j < 4; ++j) v[j] = (base + j < N) ? counts[base + j] : 0;
  const int tot = v[0] + v[1] + v[2] + v[3];
  tsum[t] = tot;
  __syncthreads();
  for (int off = 1; off < 256; off <<= 1) {
    const int add = (t >= off) ? tsum[t - off] : 0;
    __syncthreads();
    tsum[t] += add;
    __syncthreads();
  }
  int run = bsums[blockIdx.x] + tsum[t] - tot;  // grid-wide exclusive prefix
#pragma unroll
  for (int j = 0; j < 4; ++j) {
    const int idx = base + j;
    if (idx < N) {
      row_start[idx] = run;
      cursor[idx] = run;
      run += v[j];
    }
  }
}

__global__ void dis_kernel(float* __restrict__ deg_dis, int N) {
  const int i = blockIdx.x * blockDim.x + threadIdx.x;
  if (i < N) deg_dis[i] = rsqrtf(deg_dis[i] + 1.0f);
}

// csr[pos] = {src, norm} grouped by dst via cursor.
__global__ void fill_csr(const int* __restrict__ ei, const int* __restrict__ flag,
                         const float* __restrict__ ew, const float* __restrict__ dis,
                         int* __restrict__ cursor, int2* __restrict__ csr, int E) {
  const int e = blockIdx.x * blockDim.x + threadIdx.x;
  if (e >= E) return;
  const int use64 = flag[0];
  const int s = use64 ? ei[2 * e] : ei[e];
  const int d = use64 ? ei[2 * (E + e)] : ei[E + e];
  const float nm = dis[s] * ew[e] * dis[d];
  const int pos = atomicAdd(&cursor[d], 1);
  csr[pos] = make_int2(s, __float_as_int(nm));
}

// C[N x M] = A[N x 128] @ B[128 x M].  64x64 block tile, 4x4 thread tile.
__global__ __launch_bounds__(256, 2)
void gemm_k128(const float* __restrict__ A, const float* __restrict__ B,
               float* __restrict__ C, int N, int M) {
  __shared__ float As[64][132];
  __shared__ float Bs[128][64];
  const int tid = threadIdx.x;
  const int row0 = blockIdx.x << 6;
  const int col0 = blockIdx.y << 6;

  {
    const int rbase = tid >> 5;
    const int k = (tid & 31) << 2;
#pragma unroll
    for (int it = 0; it < 8; ++it) {
      const int r = rbase + (it << 3);
      const int row = row0 + r;
      float4 v = make_float4(0.f, 0.f, 0.f, 0.f);
      if (row < N) v = *(const float4*)(A + (long long)row * 128 + k);
      *(float4*)&As[r][k] = v;
    }
  }
  {
    const int kbase = tid >> 4;
    const int c = (tid & 15) << 2;
#pragma unroll
    for (int it = 0; it < 8; ++it) {
      const int kk = kbase + (it << 4);
      *(float4*)&Bs[kk][c] = *(const float4*)(B + (long long)kk * M + col0 + c);
    }
  }
  __syncthreads();

  const int tx = tid & 15;
  const int ty = tid >> 4;
  float acc[4][4] = {{0.f}};
#pragma unroll 4
  for (int k = 0; k < 128; ++k) {
    const float4 b = *(const float4*)&Bs[k][tx << 2];
    const float a0 = As[(ty << 2) + 0][k];
    const float a1 = As[(ty << 2) + 1][k];
    const float a2 = As[(ty << 2) + 2][k];
    const float a3 = As[(ty << 2) + 3][k];
    acc[0][0] = fmaf(a0, b.x, acc[0][0]); acc[0][1] = fmaf(a0, b.y, acc[0][1]);
    acc[0][2] = fmaf(a0, b.z, acc[0][2]); acc[0][3] = fmaf(a0, b.w, acc[0][3]);
    acc[1][0] = fmaf(a1, b.x, acc[1][0]); acc[1][1] = fmaf(a1, b.y, acc[1][1]);
    acc[1][2] = fmaf(a1, b.z, acc[1][2]); acc[1][3] = fmaf(a1, b.w, acc[1][3]);
    acc[2][0] = fmaf(a2, b.x, acc[2][0]); acc[2][1] = fmaf(a2, b.y, acc[2][1]);
    acc[2][2] = fmaf(a2, b.z, acc[2][2]); acc[2][3] = fmaf(a2, b.w, acc[2][3]);
    acc[3][0] = fmaf(a3, b.x, acc[3][0]); acc[3][1] = fmaf(a3, b.y, acc[3][1]);
    acc[3][2] = fmaf(a3, b.z, acc[3][2]); acc[3][3] = fmaf(a3, b.w, acc[3][3]);
  }

#pragma unroll
  for (int i = 0; i < 4; ++i) {
    const int row = row0 + (ty << 2) + i;
    if (row < N)
      *(float4*)(C + (long long)row * M + col0 + (tx << 2)) =
          make_float4(acc[i][0], acc[i][1], acc[i][2], acc[i][3]);
  }
}

// One wave per dst node, 4-way edge unroll for MLP.
template <int M, bool RELU>
__global__ __launch_bounds__(256)
void gather(const int2* __restrict__ csr, const int* __restrict__ row_start,
            const float* __restrict__ xw, const float* __restrict__ dis,
            const float* __restrict__ bias, float* __restrict__ out, int N) {
  const int node = (blockIdx.x << 2) + (threadIdx.x >> 6);
  const int lane = threadIdx.x & 63;
  if (node >= N) return;
  const int beg = row_start[node];
  const int end = row_start[node + 1];
  if (M == 128) {
    const int c = lane << 1;
    float2 a0 = make_float2(0.f, 0.f), a1 = a0, a2 = a0, a3 = a0;
    int e = beg;
    for (; e + 3 < end; e += 4) {
      const int2 p0 = csr[e + 0];
      const int2 p1 = csr[e + 1];
      const int2 p2 = csr[e + 2];
      const int2 p3 = csr[e + 3];
      const float2 v0 = *(const float2*)(xw + (long long)p0.x * 128 + c);
      const float2 v1 = *(const float2*)(xw + (long long)p1.x * 128 + c);
      const float2 v2 = *(const float2*)(xw + (long long)p2.x * 128 + c);
      const float2 v3 = *(const float2*)(xw + (long long)p3.x * 128 + c);
      const float n0 = __int_as_float(p0.y), n1 = __int_as_float(p1.y);
      const float n2 = __int_as_float(p2.y), n3 = __int_as_float(p3.y);
      a0.x = fmaf(n0, v0.x, a0.x); a0.y = fmaf(n0, v0.y, a0.y);
      a1.x = fmaf(n1, v1.x, a1.x); a1.y = fmaf(n1, v1.y, a1.y);
      a2.x = fmaf(n2, v2.x, a2.x); a2.y = fmaf(n2, v2.y, a2.y);
      a3.x = fmaf(n3, v3.x, a3.x); a3.y = fmaf(n3, v3.y, a3.y);
    }
    for (; e < end; ++e) {
      const int2 p = csr[e];
      const float nm = __int_as_float(p.y);
      const float2 v = *(const float2*)(xw + (long long)p.x * 128 + c);
      a0.x = fmaf(nm, v.x, a0.x); a0.y = fmaf(nm, v.y, a0.y);
    }
    float2 acc;
    acc.x = (a0.x + a1.x) + (a2.x + a3.x);
    acc.y = (a0.y + a1.y) + (a2.y + a3.y);
    const float di = dis[node];
    const float dsq = di * di;
    const float2 sv = *(const float2*)(xw + (long long)node * 128 + c);
    const float2 bv = *(const float2*)(bias + c);
    acc.x = fmaf(dsq, sv.x, acc.x) + bv.x;
    acc.y = fmaf(dsq, sv.y, acc.y) + bv.y;
    if (RELU) { acc.x = fmaxf(acc.x, 0.f); acc.y = fmaxf(acc.y, 0.f); }
    *(float2*)(out + (long long)node * 128 + c) = acc;
  } else {
    float a0 = 0.f, a1 = 0.f, a2 = 0.f, a3 = 0.f;
    int e = beg;
    for (; e + 3 < end; e += 4) {
      const int2 p0 = csr[e + 0];
      const int2 p1 = csr[e + 1];
      const int2 p2 = csr[e + 2];
      const int2 p3 = csr[e + 3];
      const float v0 = xw[(long long)p0.x * 64 + lane];
      const float v1 = xw[(long long)p1.x * 64 + lane];
      const float v2 = xw[(long long)p2.x * 64 + lane];
      const float v3 = xw[(long long)p3.x * 64 + lane];
      a0 = fmaf(__int_as_float(p0.y), v0, a0);
      a1 = fmaf(__int_as_float(p1.y), v1, a1);
      a2 = fmaf(__int_as_float(p2.y), v2, a2);
      a3 = fmaf(__int_as_float(p3.y), v3, a3);
    }
    for (; e < end; ++e) {
      const int2 p = csr[e];
      a0 = fmaf(__int_as_float(p.y), xw[(long long)p.x * 64 + lane], a0);
    }
    float acc = (a0 + a1) + (a2 + a3);
    const float di = dis[node];
    float r = fmaf(di * di, xw[(long long)node * 64 + lane], acc) + bias[lane];
    if (RELU) r = fmaxf(r, 0.f);
    out[(long long)node * 64 + lane] = r;
  }
}

extern "C" void kernel_launch(void* const* d_in, const int* in_sizes, int n_in,
                              void* d_out, int out_size, void* d_ws, size_t ws_size,
                              hipStream_t stream) {
  const float* x  = (const float*)d_in[0];
  const int*   ei = (const int*)d_in[1];
  const float* ew = (const float*)d_in[2];
  const float* W1 = (const float*)d_in[3];
  const float* b1 = (const float*)d_in[4];
  const float* W2 = (const float*)d_in[5];
  const float* b2 = (const float*)d_in[6];
  const float* W3 = (const float*)d_in[7];
  const float* b3 = (const float*)d_in[8];
  float* out = (float*)d_out;

  const int IN = 128, HID = 128;
  const int N = in_sizes[0] / IN;   // 100000
  const int E = in_sizes[2];        // 1600000

  char* ws = (char*)d_ws;
  float* dis       = (float*)(ws);
  int*   flag      = (int*)(ws + (512u << 10));
  int*   bsums     = (int*)(ws + (768u << 10));
  int*   row_start = (int*)(ws + (1u << 20));
  int*   cursor    = (int*)(ws + (1u << 20) + (512u << 10));
  int2*  csr       = (int2*)(ws + (2u << 20));
  float* bufA      = (float*)(ws + (16u << 20));
  float* bufB      = (float*)(ws + (68u << 20));

  const dim3 blk(256);
  const int gE = (E + 255) / 256;
  const int gN = (N + 255) / 256;
  const int B = (N + 1023) / 1024;   // scan blocks (98 for N=100K)

  // --- CSR build + normalization coefficients ---
  hipLaunchKernelGGL(detect_i64, dim3(1), blk, 0, stream, ei, flag);
  hipLaunchKernelGGL(zero_ints, dim3(128), blk, 0, stream, (int*)dis, N);
  hipLaunchKernelGGL(zero_ints, dim3(128), blk, 0, stream, cursor, N);
  hipLaunchKernelGGL(count_deg, dim3(gE), blk, 0, stream, ei, flag, ew, cursor, dis, E);
  hipLaunchKernelGGL(scan_phase1, dim3(B), blk, 0, stream, cursor, bsums, N);
  hipLaunchKernelGGL(scan_phase2, dim3(1), dim3(1024), 0, stream, bsums, row_start, B, N);
  hipLaunchKernelGGL(scan_phase3, dim3(B), blk, 0, stream, cursor, bsums, row_start, cursor, N);
  hipLaunchKernelGGL(dis_kernel, dim3(gN), blk, 0, stream, dis, N);
  hipLaunchKernelGGL(fill_csr, dim3(gE), blk, 0, stream, ei, flag, ew, dis, cursor, csr, E);

  const int gRows = (N + 63) / 64;
  const int gGather = (N + 3) / 4;

  // --- layer 1 ---
  hipLaunchKernelGGL(gemm_k128, dim3(gRows, HID / 64), blk, 0, stream, x, W1, bufA, N, HID);
  hipLaunchKernelGGL((gather<128, true>), dim3(gGather), blk, 0, stream,
                     csr, row_start, bufA, dis, b1, bufB, N);
  // --- layer 2 ---
  hipLaunchKernelGGL(gemm_k128, dim3(gRows, HID / 64), blk, 0, stream, bufB, W2, bufA, N, HID);
  hipLaunchKernelGGL((gather<128, true>), dim3(gGather), blk, 0, stream,
                     csr, row_start, bufA, dis, b2, bufB, N);
  // --- layer 3 ---
  hipLaunchKernelGGL(gemm_k128, dim3(gRows, 1), blk, 0, stream, bufB, W3, bufA, N, 64);
  hipLaunchKernelGGL((gather<64, false>), dim3(gGather), blk, 0, stream,
                     csr, row_start, bufA, dis, b3, out, N);
}

// Round 4
// 707.647 us; speedup vs baseline: 2.9212x; 1.1440x over previous
//
#include <hip/hip_runtime.h>

// ---------------------------------------------------------------------------
// GCN 3-layer forward, CSR-gather, packed u64 count+deg atomic (1 atomic/edge).
// d_ws layout (max 119.2 MB, proven safe):
//   [0)      packed: N u64 {hi=count, lo=fixed24 sum(ew)}   (800 KB)
//   [1 MB)   dis: N floats
//   [1.5 MB) flag: 1 int;  [1.5MB+4K) bsums: up to 1024 ints
//   [1.6 MB) row_start: (N+1) ints
//   [2.5 MB) csr: E x int2 {src, norm-as-int}  (12.8 MB, ends 15.3 MB)
//   [16 MB)  bufA: N*128 floats  (eseq E ints aliases its head during CSR build)
//   [68 MB)  bufB: N*128 floats
// ---------------------------------------------------------------------------

__global__ void zero_ints(int* __restrict__ p, int n) {
  int i = blockIdx.x * blockDim.x + threadIdx.x;
  const int stride = gridDim.x * blockDim.x;
  for (; i < n; i += stride) p[i] = 0;
}

// Detect whether edge_index arrived as int64 (odd int32 words all zero).
__global__ void detect_i64(const int* __restrict__ ei, int* __restrict__ flag) {
  __shared__ int nonzero;
  if (threadIdx.x == 0) nonzero = 0;
  __syncthreads();
  int acc = 0;
#pragma unroll
  for (int it = 0; it < 8; ++it) {
    const int j = threadIdx.x + (it << 8);
    acc |= ei[2 * j + 1];
  }
  if (acc != 0) atomicOr(&nonzero, 1);
  __syncthreads();
  if (threadIdx.x == 0) flag[0] = (nonzero == 0) ? 1 : 0;
}

// One packed u64 atomic per edge: hi += 1 (count), lo += ew * 2^24 (deg).
// Returned old hi word = this edge's sequence slot within its dst row.
__global__ void count_deg_pack(const int* __restrict__ ei, const int* __restrict__ flag,
                               const float* __restrict__ ew,
                               unsigned long long* __restrict__ packed,
                               int* __restrict__ eseq, int E) {
  const int e = blockIdx.x * blockDim.x + threadIdx.x;
  if (e >= E) return;
  const int use64 = flag[0];
  const int d = use64 ? ei[2 * (E + e)] : ei[E + e];
  const unsigned int fx = (unsigned int)(ew[e] * 16777216.0f);  // 2^24 fixed point
  const unsigned long long old =
      atomicAdd(&packed[d], (1ULL << 32) | (unsigned long long)fx);
  eseq[e] = (int)(old >> 32);
}

// ---- 3-phase device-wide exclusive scan over hi words (chunk = 1024/block) ----
__global__ __launch_bounds__(256)
void scan_phase1(const unsigned long long* __restrict__ packed,
                 int* __restrict__ bsums, int N) {
  __shared__ int red[256];
  const int t = threadIdx.x;
  const int base = blockIdx.x * 1024 + t * 4;
  int s = 0;
#pragma unroll
  for (int j = 0; j < 4; ++j) {
    const int idx = base + j;
    if (idx < N) s += (int)(packed[idx] >> 32);
  }
  red[t] = s;
  __syncthreads();
  for (int off = 128; off > 0; off >>= 1) {
    if (t < off) red[t] += red[t + off];
    __syncthreads();
  }
  if (t == 0) bsums[blockIdx.x] = red[0];
}

__global__ __launch_bounds__(1024)
void scan_phase2(int* __restrict__ bsums, int* __restrict__ row_start, int B, int N) {
  __shared__ int s[1024];
  const int t = threadIdx.x;
  const int v = (t < B) ? bsums[t] : 0;
  s[t] = v;
  __syncthreads();
  for (int off = 1; off < 1024; off <<= 1) {
    const int add = (t >= off) ? s[t - off] : 0;
    __syncthreads();
    s[t] += add;
    __syncthreads();
  }
  if (t < B) bsums[t] = s[t] - v;           // exclusive prefix of block sums
  if (t == B - 1) row_start[N] = s[t];      // total
}

__global__ __launch_bounds__(256)
void scan_phase3(const unsigned long long* __restrict__ packed,
                 const int* __restrict__ bsums, int* __restrict__ row_start, int N) {
  __shared__ int tsum[256];
  const int t = threadIdx.x;
  const int base = blockIdx.x * 1024 + t * 4;
  int v[4];
#pragma unroll
  for (int j = 0; j < 4; ++j)
    v[j] = (base + j < N) ? (int)(packed[base + j] >> 32) : 0;
  const int tot = v[0] + v[1] + v[2] + v[3];
  tsum[t] = tot;
  __syncthreads();
  for (int off = 1; off < 256; off <<= 1) {
    const int add = (t >= off) ? tsum[t - off] : 0;
    __syncthreads();
    tsum[t] += add;
    __syncthreads();
  }
  int run = bsums[blockIdx.x] + tsum[t] - tot;  // grid-wide exclusive prefix
#pragma unroll
  for (int j = 0; j < 4; ++j) {
    const int idx = base + j;
    if (idx < N) {
      row_start[idx] = run;
      run += v[j];
    }
  }
}

__global__ void dis_kernel(const unsigned long long* __restrict__ packed,
                           float* __restrict__ dis, int N) {
  const int i = blockIdx.x * blockDim.x + threadIdx.x;
  if (i < N) {
    const float deg = (float)(unsigned int)packed[i] * (1.0f / 16777216.0f);
    dis[i] = rsqrtf(deg + 1.0f);
  }
}

// csr[row_start[dst] + eseq[e]] = {src, norm}.  No atomics.
__global__ void fill_csr(const int* __restrict__ ei, const int* __restrict__ flag,
                         const float* __restrict__ ew, const float* __restrict__ dis,
                         const int* __restrict__ row_start, const int* __restrict__ eseq,
                         int2* __restrict__ csr, int E) {
  const int e = blockIdx.x * blockDim.x + threadIdx.x;
  if (e >= E) return;
  const int use64 = flag[0];
  const int s = use64 ? ei[2 * e] : ei[e];
  const int d = use64 ? ei[2 * (E + e)] : ei[E + e];
  const float nm = dis[s] * ew[e] * dis[d];
  const int pos = row_start[d] + eseq[e];
  csr[pos] = make_int2(s, __float_as_int(nm));
}

// C[N x M] = A[N x 128] @ B[128 x M].  64x64 block tile, 4x4 thread tile.
__global__ __launch_bounds__(256, 2)
void gemm_k128(const float* __restrict__ A, const float* __restrict__ B,
               float* __restrict__ C, int N, int M) {
  __shared__ float As[64][132];
  __shared__ float Bs[128][64];
  const int tid = threadIdx.x;
  const int row0 = blockIdx.x << 6;
  const int col0 = blockIdx.y << 6;

  {
    const int rbase = tid >> 5;
    const int k = (tid & 31) << 2;
#pragma unroll
    for (int it = 0; it < 8; ++it) {
      const int r = rbase + (it << 3);
      const int row = row0 + r;
      float4 v = make_float4(0.f, 0.f, 0.f, 0.f);
      if (row < N) v = *(const float4*)(A + (long long)row * 128 + k);
      *(float4*)&As[r][k] = v;
    }
  }
  {
    const int kbase = tid >> 4;
    const int c = (tid & 15) << 2;
#pragma unroll
    for (int it = 0; it < 8; ++it) {
      const int kk = kbase + (it << 4);
      *(float4*)&Bs[kk][c] = *(const float4*)(B + (long long)kk * M + col0 + c);
    }
  }
  __syncthreads();

  const int tx = tid & 15;
  const int ty = tid >> 4;
  float acc[4][4] = {{0.f}};
#pragma unroll 4
  for (int k = 0; k < 128; ++k) {
    const float4 b = *(const float4*)&Bs[k][tx << 2];
    const float a0 = As[(ty << 2) + 0][k];
    const float a1 = As[(ty << 2) + 1][k];
    const float a2 = As[(ty << 2) + 2][k];
    const float a3 = As[(ty << 2) + 3][k];
    acc[0][0] = fmaf(a0, b.x, acc[0][0]); acc[0][1] = fmaf(a0, b.y, acc[0][1]);
    acc[0][2] = fmaf(a0, b.z, acc[0][2]); acc[0][3] = fmaf(a0, b.w, acc[0][3]);
    acc[1][0] = fmaf(a1, b.x, acc[1][0]); acc[1][1] = fmaf(a1, b.y, acc[1][1]);
    acc[1][2] = fmaf(a1, b.z, acc[1][2]); acc[1][3] = fmaf(a1, b.w, acc[1][3]);
    acc[2][0] = fmaf(a2, b.x, acc[2][0]); acc[2][1] = fmaf(a2, b.y, acc[2][1]);
    acc[2][2] = fmaf(a2, b.z, acc[2][2]); acc[2][3] = fmaf(a2, b.w, acc[2][3]);
    acc[3][0] = fmaf(a3, b.x, acc[3][0]); acc[3][1] = fmaf(a3, b.y, acc[3][1]);
    acc[3][2] = fmaf(a3, b.z, acc[3][2]); acc[3][3] = fmaf(a3, b.w, acc[3][3]);
  }

#pragma unroll
  for (int i = 0; i < 4; ++i) {
    const int row = row0 + (ty << 2) + i;
    if (row < N)
      *(float4*)(C + (long long)row * M + col0 + (tx << 2)) =
          make_float4(acc[i][0], acc[i][1], acc[i][2], acc[i][3]);
  }
}

// One wave per dst node, 4-way edge unroll for MLP.
template <int M, bool RELU>
__global__ __launch_bounds__(256)
void gather(const int2* __restrict__ csr, const int* __restrict__ row_start,
            const float* __restrict__ xw, const float* __restrict__ dis,
            const float* __restrict__ bias, float* __restrict__ out, int N) {
  const int node = (blockIdx.x << 2) + (threadIdx.x >> 6);
  const int lane = threadIdx.x & 63;
  if (node >= N) return;
  const int beg = row_start[node];
  const int end = row_start[node + 1];
  if (M == 128) {
    const int c = lane << 1;
    float2 a0 = make_float2(0.f, 0.f), a1 = a0, a2 = a0, a3 = a0;
    int e = beg;
    for (; e + 3 < end; e += 4) {
      const int2 p0 = csr[e + 0];
      const int2 p1 = csr[e + 1];
      const int2 p2 = csr[e + 2];
      const int2 p3 = csr[e + 3];
      const float2 v0 = *(const float2*)(xw + (long long)p0.x * 128 + c);
      const float2 v1 = *(const float2*)(xw + (long long)p1.x * 128 + c);
      const float2 v2 = *(const float2*)(xw + (long long)p2.x * 128 + c);
      const float2 v3 = *(const float2*)(xw + (long long)p3.x * 128 + c);
      const float n0 = __int_as_float(p0.y), n1 = __int_as_float(p1.y);
      const float n2 = __int_as_float(p2.y), n3 = __int_as_float(p3.y);
      a0.x = fmaf(n0, v0.x, a0.x); a0.y = fmaf(n0, v0.y, a0.y);
      a1.x = fmaf(n1, v1.x, a1.x); a1.y = fmaf(n1, v1.y, a1.y);
      a2.x = fmaf(n2, v2.x, a2.x); a2.y = fmaf(n2, v2.y, a2.y);
      a3.x = fmaf(n3, v3.x, a3.x); a3.y = fmaf(n3, v3.y, a3.y);
    }
    for (; e < end; ++e) {
      const int2 p = csr[e];
      const float nm = __int_as_float(p.y);
      const float2 v = *(const float2*)(xw + (long long)p.x * 128 + c);
      a0.x = fmaf(nm, v.x, a0.x); a0.y = fmaf(nm, v.y, a0.y);
    }
    float2 acc;
    acc.x = (a0.x + a1.x) + (a2.x + a3.x);
    acc.y = (a0.y + a1.y) + (a2.y + a3.y);
    const float di = dis[node];
    const float dsq = di * di;
    const float2 sv = *(const float2*)(xw + (long long)node * 128 + c);
    const float2 bv = *(const float2*)(bias + c);
    acc.x = fmaf(dsq, sv.x, acc.x) + bv.x;
    acc.y = fmaf(dsq, sv.y, acc.y) + bv.y;
    if (RELU) { acc.x = fmaxf(acc.x, 0.f); acc.y = fmaxf(acc.y, 0.f); }
    *(float2*)(out + (long long)node * 128 + c) = acc;
  } else {
    float a0 = 0.f, a1 = 0.f, a2 = 0.f, a3 = 0.f;
    int e = beg;
    for (; e + 3 < end; e += 4) {
      const int2 p0 = csr[e + 0];
      const int2 p1 = csr[e + 1];
      const int2 p2 = csr[e + 2];
      const int2 p3 = csr[e + 3];
      const float v0 = xw[(long long)p0.x * 64 + lane];
      const float v1 = xw[(long long)p1.x * 64 + lane];
      const float v2 = xw[(long long)p2.x * 64 + lane];
      const float v3 = xw[(long long)p3.x * 64 + lane];
      a0 = fmaf(__int_as_float(p0.y), v0, a0);
      a1 = fmaf(__int_as_float(p1.y), v1, a1);
      a2 = fmaf(__int_as_float(p2.y), v2, a2);
      a3 = fmaf(__int_as_float(p3.y), v3, a3);
    }
    for (; e < end; ++e) {
      const int2 p = csr[e];
      a0 = fmaf(__int_as_float(p.y), xw[(long long)p.x * 64 + lane], a0);
    }
    float acc = (a0 + a1) + (a2 + a3);
    const float di = dis[node];
    float r = fmaf(di * di, xw[(long long)node * 64 + lane], acc) + bias[lane];
    if (RELU) r = fmaxf(r, 0.f);
    out[(long long)node * 64 + lane] = r;
  }
}

extern "C" void kernel_launch(void* const* d_in, const int* in_sizes, int n_in,
                              void* d_out, int out_size, void* d_ws, size_t ws_size,
                              hipStream_t stream) {
  const float* x  = (const float*)d_in[0];
  const int*   ei = (const int*)d_in[1];
  const float* ew = (const float*)d_in[2];
  const float* W1 = (const float*)d_in[3];
  const float* b1 = (const float*)d_in[4];
  const float* W2 = (const float*)d_in[5];
  const float* b2 = (const float*)d_in[6];
  const float* W3 = (const float*)d_in[7];
  const float* b3 = (const float*)d_in[8];
  float* out = (float*)d_out;

  const int IN = 128, HID = 128;
  const int N = in_sizes[0] / IN;   // 100000
  const int E = in_sizes[2];        // 1600000

  char* ws = (char*)d_ws;
  unsigned long long* packed = (unsigned long long*)(ws);
  float* dis       = (float*)(ws + (1u << 20));
  int*   flag      = (int*)(ws + (1536u << 10));
  int*   bsums     = (int*)(ws + (1536u << 10) + 4096);
  int*   row_start = (int*)(ws + (1600u << 10));
  int2*  csr       = (int2*)(ws + (2560u << 10));
  float* bufA      = (float*)(ws + (16u << 20));
  float* bufB      = (float*)(ws + (68u << 20));
  int*   eseq      = (int*)bufA;   // dead before layer-1 GEMM writes bufA

  const dim3 blk(256);
  const int gE = (E + 255) / 256;
  const int gN = (N + 255) / 256;
  const int B = (N + 1023) / 1024;   // scan blocks (98 for N=100K)

  // --- CSR build + normalization coefficients ---
  hipLaunchKernelGGL(detect_i64, dim3(1), blk, 0, stream, ei, flag);
  hipLaunchKernelGGL(zero_ints, dim3(128), blk, 0, stream, (int*)packed, 2 * N);
  hipLaunchKernelGGL(count_deg_pack, dim3(gE), blk, 0, stream, ei, flag, ew, packed, eseq, E);
  hipLaunchKernelGGL(scan_phase1, dim3(B), blk, 0, stream, packed, bsums, N);
  hipLaunchKernelGGL(scan_phase2, dim3(1), dim3(1024), 0, stream, bsums, row_start, B, N);
  hipLaunchKernelGGL(scan_phase3, dim3(B), blk, 0, stream, packed, bsums, row_start, N);
  hipLaunchKernelGGL(dis_kernel, dim3(gN), blk, 0, stream, packed, dis, N);
  hipLaunchKernelGGL(fill_csr, dim3(gE), blk, 0, stream, ei, flag, ew, dis, row_start, eseq, csr, E);

  const int gRows = (N + 63) / 64;
  const int gGather = (N + 3) / 4;

  // --- layer 1 ---
  hipLaunchKernelGGL(gemm_k128, dim3(gRows, HID / 64), blk, 0, stream, x, W1, bufA, N, HID);
  hipLaunchKernelGGL((gather<128, true>), dim3(gGather), blk, 0, stream,
                     csr, row_start, bufA, dis, b1, bufB, N);
  // --- layer 2 ---
  hipLaunchKernelGGL(gemm_k128, dim3(gRows, HID / 64), blk, 0, stream, bufB, W2, bufA, N, HID);
  hipLaunchKernelGGL((gather<128, true>), dim3(gGather), blk, 0, stream,
                     csr, row_start, bufA, dis, b2, bufB, N);
  // --- layer 3 ---
  hipLaunchKernelGGL(gemm_k128, dim3(gRows, 1), blk, 0, stream, bufB, W3, bufA, N, 64);
  hipLaunchKernelGGL((gather<64, false>), dim3(gGather), blk, 0, stream,
                     csr, row_start, bufA, dis, b3, out, N);
}

// Round 5
// 618.772 us; speedup vs baseline: 3.3408x; 1.1436x over previous
//
#include <hip/hip_runtime.h>

// ---------------------------------------------------------------------------
// GCN 3-layer forward. CSR-gather with bf16 gather operand.
// d_ws layout (max 119.2 MB, proven safe):
//   [0)      packed: N u64 {hi=count, lo=fixed24 sum(ew)}   (800 KB)
//   [1 MB)   dis: N floats
//   [1.5 MB) flag: 1 int;  [1.5MB+4K) bsums: up to 1024 ints
//   [1.6 MB) row_start: (N+1) ints
//   [2.5 MB) csr: E x int2 {src, norm-as-int}  (12.8 MB, ends 15.3 MB)
//   [16 MB)  bufA: N*128 bf16 xw (25.6 MB; eseq E ints aliases its head)
//   [68 MB)  bufB: N*128 floats (gather output / next GEMM input)
// ---------------------------------------------------------------------------

__device__ inline unsigned short f2bf(float f) {   // RNE f32 -> bf16
  unsigned int u = __float_as_uint(f);
  u += 0x7fffu + ((u >> 16) & 1u);
  return (unsigned short)(u >> 16);
}

__global__ void zero_ints(int* __restrict__ p, int n) {
  int i = blockIdx.x * blockDim.x + threadIdx.x;
  const int stride = gridDim.x * blockDim.x;
  for (; i < n; i += stride) p[i] = 0;
}

// Detect whether edge_index arrived as int64 (odd int32 words all zero).
__global__ void detect_i64(const int* __restrict__ ei, int* __restrict__ flag) {
  __shared__ int nonzero;
  if (threadIdx.x == 0) nonzero = 0;
  __syncthreads();
  int acc = 0;
#pragma unroll
  for (int it = 0; it < 8; ++it) {
    const int j = threadIdx.x + (it << 8);
    acc |= ei[2 * j + 1];
  }
  if (acc != 0) atomicOr(&nonzero, 1);
  __syncthreads();
  if (threadIdx.x == 0) flag[0] = (nonzero == 0) ? 1 : 0;
}

// One packed u64 atomic per edge: hi += 1 (count), lo += ew * 2^24 (deg).
__global__ void count_deg_pack(const int* __restrict__ ei, const int* __restrict__ flag,
                               const float* __restrict__ ew,
                               unsigned long long* __restrict__ packed,
                               int* __restrict__ eseq, int E) {
  const int e = blockIdx.x * blockDim.x + threadIdx.x;
  if (e >= E) return;
  const int use64 = flag[0];
  const int d = use64 ? ei[2 * (E + e)] : ei[E + e];
  const unsigned int fx = (unsigned int)(ew[e] * 16777216.0f);  // 2^24 fixed point
  const unsigned long long old =
      atomicAdd(&packed[d], (1ULL << 32) | (unsigned long long)fx);
  eseq[e] = (int)(old >> 32);
}

// ---- 3-phase device-wide exclusive scan over hi words ----
__global__ __launch_bounds__(256)
void scan_phase1(const unsigned long long* __restrict__ packed,
                 int* __restrict__ bsums, int N) {
  __shared__ int red[256];
  const int t = threadIdx.x;
  const int base = blockIdx.x * 1024 + t * 4;
  int s = 0;
#pragma unroll
  for (int j = 0; j < 4; ++j) {
    const int idx = base + j;
    if (idx < N) s += (int)(packed[idx] >> 32);
  }
  red[t] = s;
  __syncthreads();
  for (int off = 128; off > 0; off >>= 1) {
    if (t < off) red[t] += red[t + off];
    __syncthreads();
  }
  if (t == 0) bsums[blockIdx.x] = red[0];
}

__global__ __launch_bounds__(1024)
void scan_phase2(int* __restrict__ bsums, int* __restrict__ row_start, int B, int N) {
  __shared__ int s[1024];
  const int t = threadIdx.x;
  const int v = (t < B) ? bsums[t] : 0;
  s[t] = v;
  __syncthreads();
  for (int off = 1; off < 1024; off <<= 1) {
    const int add = (t >= off) ? s[t - off] : 0;
    __syncthreads();
    s[t] += add;
    __syncthreads();
  }
  if (t < B) bsums[t] = s[t] - v;
  if (t == B - 1) row_start[N] = s[t];
}

__global__ __launch_bounds__(256)
void scan_phase3(const unsigned long long* __restrict__ packed,
                 const int* __restrict__ bsums, int* __restrict__ row_start, int N) {
  __shared__ int tsum[256];
  const int t = threadIdx.x;
  const int base = blockIdx.x * 1024 + t * 4;
  int v[4];
#pragma unroll
  for (int j = 0; j < 4; ++j)
    v[j] = (base + j < N) ? (int)(packed[base + j] >> 32) : 0;
  const int tot = v[0] + v[1] + v[2] + v[3];
  tsum[t] = tot;
  __syncthreads();
  for (int off = 1; off < 256; off <<= 1) {
    const int add = (t >= off) ? tsum[t - off] : 0;
    __syncthreads();
    tsum[t] += add;
    __syncthreads();
  }
  int run = bsums[blockIdx.x] + tsum[t] - tot;
#pragma unroll
  for (int j = 0; j < 4; ++j) {
    const int idx = base + j;
    if (idx < N) {
      row_start[idx] = run;
      run += v[j];
    }
  }
}

__global__ void dis_kernel(const unsigned long long* __restrict__ packed,
                           float* __restrict__ dis, int N) {
  const int i = blockIdx.x * blockDim.x + threadIdx.x;
  if (i < N) {
    const float deg = (float)(unsigned int)packed[i] * (1.0f / 16777216.0f);
    dis[i] = rsqrtf(deg + 1.0f);
  }
}

// csr[row_start[dst] + eseq[e]] = {src, norm}.  No atomics.
__global__ void fill_csr(const int* __restrict__ ei, const int* __restrict__ flag,
                         const float* __restrict__ ew, const float* __restrict__ dis,
                         const int* __restrict__ row_start, const int* __restrict__ eseq,
                         int2* __restrict__ csr, int E) {
  const int e = blockIdx.x * blockDim.x + threadIdx.x;
  if (e >= E) return;
  const int use64 = flag[0];
  const int s = use64 ? ei[2 * e] : ei[e];
  const int d = use64 ? ei[2 * (E + e)] : ei[E + e];
  const float nm = dis[s] * ew[e] * dis[d];
  const int pos = row_start[d] + eseq[e];
  csr[pos] = make_int2(s, __float_as_int(nm));
}

// C[N x M] = A[N x 128] @ B[128 x M], C stored as bf16. 64x64 tile, 4x4/thread.
__global__ __launch_bounds__(256, 2)
void gemm_k128_bf16out(const float* __restrict__ A, const float* __restrict__ B,
                       unsigned short* __restrict__ C, int N, int M) {
  __shared__ float As[64][132];
  __shared__ float Bs[128][64];
  const int tid = threadIdx.x;
  const int row0 = blockIdx.x << 6;
  const int col0 = blockIdx.y << 6;

  {
    const int rbase = tid >> 5;
    const int k = (tid & 31) << 2;
#pragma unroll
    for (int it = 0; it < 8; ++it) {
      const int r = rbase + (it << 3);
      const int row = row0 + r;
      float4 v = make_float4(0.f, 0.f, 0.f, 0.f);
      if (row < N) v = *(const float4*)(A + (long long)row * 128 + k);
      *(float4*)&As[r][k] = v;
    }
  }
  {
    const int kbase = tid >> 4;
    const int c = (tid & 15) << 2;
#pragma unroll
    for (int it = 0; it < 8; ++it) {
      const int kk = kbase + (it << 4);
      *(float4*)&Bs[kk][c] = *(const float4*)(B + (long long)kk * M + col0 + c);
    }
  }
  __syncthreads();

  const int tx = tid & 15;
  const int ty = tid >> 4;
  float acc[4][4] = {{0.f}};
#pragma unroll 4
  for (int k = 0; k < 128; ++k) {
    const float4 b = *(const float4*)&Bs[k][tx << 2];
    const float a0 = As[(ty << 2) + 0][k];
    const float a1 = As[(ty << 2) + 1][k];
    const float a2 = As[(ty << 2) + 2][k];
    const float a3 = As[(ty << 2) + 3][k];
    acc[0][0] = fmaf(a0, b.x, acc[0][0]); acc[0][1] = fmaf(a0, b.y, acc[0][1]);
    acc[0][2] = fmaf(a0, b.z, acc[0][2]); acc[0][3] = fmaf(a0, b.w, acc[0][3]);
    acc[1][0] = fmaf(a1, b.x, acc[1][0]); acc[1][1] = fmaf(a1, b.y, acc[1][1]);
    acc[1][2] = fmaf(a1, b.z, acc[1][2]); acc[1][3] = fmaf(a1, b.w, acc[1][3]);
    acc[2][0] = fmaf(a2, b.x, acc[2][0]); acc[2][1] = fmaf(a2, b.y, acc[2][1]);
    acc[2][2] = fmaf(a2, b.z, acc[2][2]); acc[2][3] = fmaf(a2, b.w, acc[2][3]);
    acc[3][0] = fmaf(a3, b.x, acc[3][0]); acc[3][1] = fmaf(a3, b.y, acc[3][1]);
    acc[3][2] = fmaf(a3, b.z, acc[3][2]); acc[3][3] = fmaf(a3, b.w, acc[3][3]);
  }

#pragma unroll
  for (int i = 0; i < 4; ++i) {
    const int row = row0 + (ty << 2) + i;
    if (row < N) {
      ushort4 o;
      o.x = f2bf(acc[i][0]); o.y = f2bf(acc[i][1]);
      o.z = f2bf(acc[i][2]); o.w = f2bf(acc[i][3]);
      *(ushort4*)(C + (long long)row * M + col0 + (tx << 2)) = o;
    }
  }
}

// One wave per dst node, 4-way edge unroll; xw is bf16, accumulate fp32.
template <int M, bool RELU>
__global__ __launch_bounds__(256)
void gather(const int2* __restrict__ csr, const int* __restrict__ row_start,
            const unsigned short* __restrict__ xw, const float* __restrict__ dis,
            const float* __restrict__ bias, float* __restrict__ out, int N) {
  const int node = (blockIdx.x << 2) + (threadIdx.x >> 6);
  const int lane = threadIdx.x & 63;
  if (node >= N) return;
  const int beg = row_start[node];
  const int end = row_start[node + 1];
  if (M == 128) {
    const int c = lane << 1;
    float2 a0 = make_float2(0.f, 0.f), a1 = a0, a2 = a0, a3 = a0;
    int e = beg;
    for (; e + 3 < end; e += 4) {
      const int2 p0 = csr[e + 0];
      const int2 p1 = csr[e + 1];
      const int2 p2 = csr[e + 2];
      const int2 p3 = csr[e + 3];
      const unsigned int u0 = *(const unsigned int*)(xw + (long long)p0.x * 128 + c);
      const unsigned int u1 = *(const unsigned int*)(xw + (long long)p1.x * 128 + c);
      const unsigned int u2 = *(const unsigned int*)(xw + (long long)p2.x * 128 + c);
      const unsigned int u3 = *(const unsigned int*)(xw + (long long)p3.x * 128 + c);
      const float n0 = __int_as_float(p0.y), n1 = __int_as_float(p1.y);
      const float n2 = __int_as_float(p2.y), n3 = __int_as_float(p3.y);
      a0.x = fmaf(n0, __uint_as_float(u0 << 16), a0.x);
      a0.y = fmaf(n0, __uint_as_float(u0 & 0xffff0000u), a0.y);
      a1.x = fmaf(n1, __uint_as_float(u1 << 16), a1.x);
      a1.y = fmaf(n1, __uint_as_float(u1 & 0xffff0000u), a1.y);
      a2.x = fmaf(n2, __uint_as_float(u2 << 16), a2.x);
      a2.y = fmaf(n2, __uint_as_float(u2 & 0xffff0000u), a2.y);
      a3.x = fmaf(n3, __uint_as_float(u3 << 16), a3.x);
      a3.y = fmaf(n3, __uint_as_float(u3 & 0xffff0000u), a3.y);
    }
    for (; e < end; ++e) {
      const int2 p = csr[e];
      const float nm = __int_as_float(p.y);
      const unsigned int u = *(const unsigned int*)(xw + (long long)p.x * 128 + c);
      a0.x = fmaf(nm, __uint_as_float(u << 16), a0.x);
      a0.y = fmaf(nm, __uint_as_float(u & 0xffff0000u), a0.y);
    }
    float2 acc;
    acc.x = (a0.x + a1.x) + (a2.x + a3.x);
    acc.y = (a0.y + a1.y) + (a2.y + a3.y);
    const float di = dis[node];
    const float dsq = di * di;
    const unsigned int su = *(const unsigned int*)(xw + (long long)node * 128 + c);
    const float2 bv = *(const float2*)(bias + c);
    acc.x = fmaf(dsq, __uint_as_float(su << 16), acc.x) + bv.x;
    acc.y = fmaf(dsq, __uint_as_float(su & 0xffff0000u), acc.y) + bv.y;
    if (RELU) { acc.x = fmaxf(acc.x, 0.f); acc.y = fmaxf(acc.y, 0.f); }
    *(float2*)(out + (long long)node * 128 + c) = acc;
  } else {
    float a0 = 0.f, a1 = 0.f, a2 = 0.f, a3 = 0.f;
    int e = beg;
    for (; e + 3 < end; e += 4) {
      const int2 p0 = csr[e + 0];
      const int2 p1 = csr[e + 1];
      const int2 p2 = csr[e + 2];
      const int2 p3 = csr[e + 3];
      const unsigned int v0 = xw[(long long)p0.x * 64 + lane];
      const unsigned int v1 = xw[(long long)p1.x * 64 + lane];
      const unsigned int v2 = xw[(long long)p2.x * 64 + lane];
      const unsigned int v3 = xw[(long long)p3.x * 64 + lane];
      a0 = fmaf(__int_as_float(p0.y), __uint_as_float(v0 << 16), a0);
      a1 = fmaf(__int_as_float(p1.y), __uint_as_float(v1 << 16), a1);
      a2 = fmaf(__int_as_float(p2.y), __uint_as_float(v2 << 16), a2);
      a3 = fmaf(__int_as_float(p3.y), __uint_as_float(v3 << 16), a3);
    }
    for (; e < end; ++e) {
      const int2 p = csr[e];
      const unsigned int v = xw[(long long)p.x * 64 + lane];
      a0 = fmaf(__int_as_float(p.y), __uint_as_float(v << 16), a0);
    }
    float acc = (a0 + a1) + (a2 + a3);
    const float di = dis[node];
    const unsigned int sv = xw[(long long)node * 64 + lane];
    float r = fmaf(di * di, __uint_as_float(sv << 16), acc) + bias[lane];
    if (RELU) r = fmaxf(r, 0.f);
    out[(long long)node * 64 + lane] = r;
  }
}

extern "C" void kernel_launch(void* const* d_in, const int* in_sizes, int n_in,
                              void* d_out, int out_size, void* d_ws, size_t ws_size,
                              hipStream_t stream) {
  const float* x  = (const float*)d_in[0];
  const int*   ei = (const int*)d_in[1];
  const float* ew = (const float*)d_in[2];
  const float* W1 = (const float*)d_in[3];
  const float* b1 = (const float*)d_in[4];
  const float* W2 = (const float*)d_in[5];
  const float* b2 = (const float*)d_in[6];
  const float* W3 = (const float*)d_in[7];
  const float* b3 = (const float*)d_in[8];
  float* out = (float*)d_out;

  const int IN = 128, HID = 128;
  const int N = in_sizes[0] / IN;   // 100000
  const int E = in_sizes[2];        // 1600000

  char* ws = (char*)d_ws;
  unsigned long long* packed = (unsigned long long*)(ws);
  float* dis       = (float*)(ws + (1u << 20));
  int*   flag      = (int*)(ws + (1536u << 10));
  int*   bsums     = (int*)(ws + (1536u << 10) + 4096);
  int*   row_start = (int*)(ws + (1600u << 10));
  int2*  csr       = (int2*)(ws + (2560u << 10));
  unsigned short* bufA = (unsigned short*)(ws + (16u << 20));  // bf16 xw
  float* bufB      = (float*)(ws + (68u << 20));
  int*   eseq      = (int*)bufA;   // dead before layer-1 GEMM writes bufA

  const dim3 blk(256);
  const int gE = (E + 255) / 256;
  const int gN = (N + 255) / 256;
  const int B = (N + 1023) / 1024;

  // --- CSR build + normalization coefficients ---
  hipLaunchKernelGGL(detect_i64, dim3(1), blk, 0, stream, ei, flag);
  hipLaunchKernelGGL(zero_ints, dim3(128), blk, 0, stream, (int*)packed, 2 * N);
  hipLaunchKernelGGL(count_deg_pack, dim3(gE), blk, 0, stream, ei, flag, ew, packed, eseq, E);
  hipLaunchKernelGGL(scan_phase1, dim3(B), blk, 0, stream, packed, bsums, N);
  hipLaunchKernelGGL(scan_phase2, dim3(1), dim3(1024), 0, stream, bsums, row_start, B, N);
  hipLaunchKernelGGL(scan_phase3, dim3(B), blk, 0, stream, packed, bsums, row_start, N);
  hipLaunchKernelGGL(dis_kernel, dim3(gN), blk, 0, stream, packed, dis, N);
  hipLaunchKernelGGL(fill_csr, dim3(gE), blk, 0, stream, ei, flag, ew, dis, row_start, eseq, csr, E);

  const int gRows = (N + 63) / 64;
  const int gGather = (N + 3) / 4;

  // --- layer 1 ---
  hipLaunchKernelGGL(gemm_k128_bf16out, dim3(gRows, HID / 64), blk, 0, stream, x, W1, bufA, N, HID);
  hipLaunchKernelGGL((gather<128, true>), dim3(gGather), blk, 0, stream,
                     csr, row_start, bufA, dis, b1, bufB, N);
  // --- layer 2 ---
  hipLaunchKernelGGL(gemm_k128_bf16out, dim3(gRows, HID / 64), blk, 0, stream, bufB, W2, bufA, N, HID);
  hipLaunchKernelGGL((gather<128, true>), dim3(gGather), blk, 0, stream,
                     csr, row_start, bufA, dis, b2, bufB, N);
  // --- layer 3 ---
  hipLaunchKernelGGL(gemm_k128_bf16out, dim3(gRows, 1), blk, 0, stream, bufB, W3, bufA, N, 64);
  hipLaunchKernelGGL((gather<64, false>), dim3(gGather), blk, 0, stream,
                     csr, row_start, bufA, dis, b3, out, N);
}

// Round 6
// 558.849 us; speedup vs baseline: 3.6990x; 1.1072x over previous
//
#include <hip/hip_runtime.h>

// ---------------------------------------------------------------------------
// GCN 3-layer forward. CSR-gather + bf16 MFMA GEMM (LDS-free fragment loads).
// d_ws layout (max ~67.6 MB used; 119.2 MB proven safe):
//   [0)      packed: N u64 {hi=count, lo=fixed24 sum(ew)}   (800 KB)
//   [1 MB)   dis: N floats
//   [1.5 MB) flag: 1 int;  [1.5MB+4K) bsums: up to 1024 ints
//   [1.6 MB) row_start: (N+1) ints
//   [2.5 MB) csr: E x int2 {src, norm-as-int}  (12.8 MB, ends 15.3 MB)
//   [15.5MB) Wt1 bf16 [128][128]; [15.6MB) Wt2; [15.7MB) Wt3 [64][128]
//   [16 MB)  bufA: N*128 bf16 xw (25.6 MB; eseq E ints aliases its head)
//   [42 MB)  hbf: N*128 bf16 (x_bf16, then h1_bf16, then h2_bf16)
// ---------------------------------------------------------------------------

typedef __attribute__((ext_vector_type(8))) short bf16x8;
typedef __attribute__((ext_vector_type(4))) float f32x4;

__device__ inline unsigned short f2bf(float f) {   // RNE f32 -> bf16
  unsigned int u = __float_as_uint(f);
  u += 0x7fffu + ((u >> 16) & 1u);
  return (unsigned short)(u >> 16);
}

__global__ void zero_ints(int* __restrict__ p, int n) {
  int i = blockIdx.x * blockDim.x + threadIdx.x;
  const int stride = gridDim.x * blockDim.x;
  for (; i < n; i += stride) p[i] = 0;
}

// Detect whether edge_index arrived as int64 (odd int32 words all zero).
__global__ void detect_i64(const int* __restrict__ ei, int* __restrict__ flag) {
  __shared__ int nonzero;
  if (threadIdx.x == 0) nonzero = 0;
  __syncthreads();
  int acc = 0;
#pragma unroll
  for (int it = 0; it < 8; ++it) {
    const int j = threadIdx.x + (it << 8);
    acc |= ei[2 * j + 1];
  }
  if (acc != 0) atomicOr(&nonzero, 1);
  __syncthreads();
  if (threadIdx.x == 0) flag[0] = (nonzero == 0) ? 1 : 0;
}

// One packed u64 atomic per edge: hi += 1 (count), lo += ew * 2^24 (deg).
__global__ void count_deg_pack(const int* __restrict__ ei, const int* __restrict__ flag,
                               const float* __restrict__ ew,
                               unsigned long long* __restrict__ packed,
                               int* __restrict__ eseq, int E) {
  const int e = blockIdx.x * blockDim.x + threadIdx.x;
  if (e >= E) return;
  const int use64 = flag[0];
  const int d = use64 ? ei[2 * (E + e)] : ei[E + e];
  const unsigned int fx = (unsigned int)(ew[e] * 16777216.0f);  // 2^24 fixed point
  const unsigned long long old =
      atomicAdd(&packed[d], (1ULL << 32) | (unsigned long long)fx);
  eseq[e] = (int)(old >> 32);
}

// ---- 3-phase device-wide exclusive scan over hi words ----
__global__ __launch_bounds__(256)
void scan_phase1(const unsigned long long* __restrict__ packed,
                 int* __restrict__ bsums, int N) {
  __shared__ int red[256];
  const int t = threadIdx.x;
  const int base = blockIdx.x * 1024 + t * 4;
  int s = 0;
#pragma unroll
  for (int j = 0; j < 4; ++j) {
    const int idx = base + j;
    if (idx < N) s += (int)(packed[idx] >> 32);
  }
  red[t] = s;
  __syncthreads();
  for (int off = 128; off > 0; off >>= 1) {
    if (t < off) red[t] += red[t + off];
    __syncthreads();
  }
  if (t == 0) bsums[blockIdx.x] = red[0];
}

__global__ __launch_bounds__(1024)
void scan_phase2(int* __restrict__ bsums, int* __restrict__ row_start, int B, int N) {
  __shared__ int s[1024];
  const int t = threadIdx.x;
  const int v = (t < B) ? bsums[t] : 0;
  s[t] = v;
  __syncthreads();
  for (int off = 1; off < 1024; off <<= 1) {
    const int add = (t >= off) ? s[t - off] : 0;
    __syncthreads();
    s[t] += add;
    __syncthreads();
  }
  if (t < B) bsums[t] = s[t] - v;
  if (t == B - 1) row_start[N] = s[t];
}

__global__ __launch_bounds__(256)
void scan_phase3(const unsigned long long* __restrict__ packed,
                 const int* __restrict__ bsums, int* __restrict__ row_start, int N) {
  __shared__ int tsum[256];
  const int t = threadIdx.x;
  const int base = blockIdx.x * 1024 + t * 4;
  int v[4];
#pragma unroll
  for (int j = 0; j < 4; ++j)
    v[j] = (base + j < N) ? (int)(packed[base + j] >> 32) : 0;
  const int tot = v[0] + v[1] + v[2] + v[3];
  tsum[t] = tot;
  __syncthreads();
  for (int off = 1; off < 256; off <<= 1) {
    const int add = (t >= off) ? tsum[t - off] : 0;
    __syncthreads();
    tsum[t] += add;
    __syncthreads();
  }
  int run = bsums[blockIdx.x] + tsum[t] - tot;
#pragma unroll
  for (int j = 0; j < 4; ++j) {
    const int idx = base + j;
    if (idx < N) {
      row_start[idx] = run;
      run += v[j];
    }
  }
}

__global__ void dis_kernel(const unsigned long long* __restrict__ packed,
                           float* __restrict__ dis, int N) {
  const int i = blockIdx.x * blockDim.x + threadIdx.x;
  if (i < N) {
    const float deg = (float)(unsigned int)packed[i] * (1.0f / 16777216.0f);
    dis[i] = rsqrtf(deg + 1.0f);
  }
}

// csr[row_start[dst] + eseq[e]] = {src, norm}.  No atomics.
__global__ void fill_csr(const int* __restrict__ ei, const int* __restrict__ flag,
                         const float* __restrict__ ew, const float* __restrict__ dis,
                         const int* __restrict__ row_start, const int* __restrict__ eseq,
                         int2* __restrict__ csr, int E) {
  const int e = blockIdx.x * blockDim.x + threadIdx.x;
  if (e >= E) return;
  const int use64 = flag[0];
  const int s = use64 ? ei[2 * e] : ei[e];
  const int d = use64 ? ei[2 * (E + e)] : ei[E + e];
  const float nm = dis[s] * ew[e] * dis[d];
  const int pos = row_start[d] + eseq[e];
  csr[pos] = make_int2(s, __float_as_int(nm));
}

// fp32 -> bf16 vectorized convert (n multiple of 4).
__global__ void conv_bf16(const float* __restrict__ in, unsigned short* __restrict__ out,
                          long long n4) {
  long long i = (long long)blockIdx.x * blockDim.x + threadIdx.x;
  const long long stride = (long long)gridDim.x * blockDim.x;
  for (; i < n4; i += stride) {
    const float4 v = ((const float4*)in)[i];
    ushort4 o;
    o.x = f2bf(v.x); o.y = f2bf(v.y); o.z = f2bf(v.z); o.w = f2bf(v.w);
    ((ushort4*)out)[i] = o;
  }
}

// W [K=128][M] fp32 -> Wt [M][K=128] bf16.
__global__ void wt_bf16(const float* __restrict__ W, unsigned short* __restrict__ Wt,
                        int M) {
  const int idx = blockIdx.x * blockDim.x + threadIdx.x;  // m*128 + k
  if (idx >= M * 128) return;
  const int m = idx >> 7;
  const int k = idx & 127;
  Wt[idx] = f2bf(W[k * M + m]);
}

// C[N x M] = A[N x 128] @ B[128 x M] via 16x16x32 bf16 MFMA, LDS-free.
// A bf16 row-major; Bt = B^T bf16 [M][128]; C bf16.
// Block = 256 thr = 4 waves; wave handles 16 rows x M cols.
template <int M>
__global__ __launch_bounds__(256)
void gemm_mfma(const unsigned short* __restrict__ A, const unsigned short* __restrict__ Bt,
               unsigned short* __restrict__ C, int N) {
  const int lane = threadIdx.x & 63;
  const int m = lane & 15;
  const int q = lane >> 4;
  const int row0 = (blockIdx.x << 6) + ((threadIdx.x >> 6) << 4);

  const bool rowok = (row0 + m) < N;
  const unsigned short* arow = A + (long long)(row0 + m) * 128 + q * 8;
  bf16x8 a[4];
  const bf16x8 zf = {0, 0, 0, 0, 0, 0, 0, 0};
#pragma unroll
  for (int kt = 0; kt < 4; ++kt)
    a[kt] = rowok ? *(const bf16x8*)(arow + kt * 32) : zf;

#pragma unroll
  for (int ct = 0; ct < M / 16; ++ct) {
    f32x4 acc = {0.f, 0.f, 0.f, 0.f};
    const unsigned short* brow = Bt + (ct * 16 + m) * 128 + q * 8;
#pragma unroll
    for (int kt = 0; kt < 4; ++kt) {
      const bf16x8 b = *(const bf16x8*)(brow + kt * 32);
      acc = __builtin_amdgcn_mfma_f32_16x16x32_bf16(a[kt], b, acc, 0, 0, 0);
    }
    // C/D layout: col = ct*16 + (lane&15), row = row0 + q*4 + reg
#pragma unroll
    for (int r = 0; r < 4; ++r) {
      const int row = row0 + q * 4 + r;
      if (row < N) C[(long long)row * M + ct * 16 + m] = f2bf(acc[r]);
    }
  }
}

// One wave per dst node, 4-way edge unroll; xw bf16, fp32 accumulate.
// OUTBF: write bf16 (hidden layers) vs fp32 (final output).
template <int M, bool RELU, bool OUTBF>
__global__ __launch_bounds__(256)
void gather(const int2* __restrict__ csr, const int* __restrict__ row_start,
            const unsigned short* __restrict__ xw, const float* __restrict__ dis,
            const float* __restrict__ bias, void* __restrict__ outp, int N) {
  const int node = (blockIdx.x << 2) + (threadIdx.x >> 6);
  const int lane = threadIdx.x & 63;
  if (node >= N) return;
  const int beg = row_start[node];
  const int end = row_start[node + 1];
  if (M == 128) {
    const int c = lane << 1;
    float2 a0 = make_float2(0.f, 0.f), a1 = a0, a2 = a0, a3 = a0;
    int e = beg;
    for (; e + 3 < end; e += 4) {
      const int2 p0 = csr[e + 0];
      const int2 p1 = csr[e + 1];
      const int2 p2 = csr[e + 2];
      const int2 p3 = csr[e + 3];
      const unsigned int u0 = *(const unsigned int*)(xw + (long long)p0.x * 128 + c);
      const unsigned int u1 = *(const unsigned int*)(xw + (long long)p1.x * 128 + c);
      const unsigned int u2 = *(const unsigned int*)(xw + (long long)p2.x * 128 + c);
      const unsigned int u3 = *(const unsigned int*)(xw + (long long)p3.x * 128 + c);
      const float n0 = __int_as_float(p0.y), n1 = __int_as_float(p1.y);
      const float n2 = __int_as_float(p2.y), n3 = __int_as_float(p3.y);
      a0.x = fmaf(n0, __uint_as_float(u0 << 16), a0.x);
      a0.y = fmaf(n0, __uint_as_float(u0 & 0xffff0000u), a0.y);
      a1.x = fmaf(n1, __uint_as_float(u1 << 16), a1.x);
      a1.y = fmaf(n1, __uint_as_float(u1 & 0xffff0000u), a1.y);
      a2.x = fmaf(n2, __uint_as_float(u2 << 16), a2.x);
      a2.y = fmaf(n2, __uint_as_float(u2 & 0xffff0000u), a2.y);
      a3.x = fmaf(n3, __uint_as_float(u3 << 16), a3.x);
      a3.y = fmaf(n3, __uint_as_float(u3 & 0xffff0000u), a3.y);
    }
    for (; e < end; ++e) {
      const int2 p = csr[e];
      const float nm = __int_as_float(p.y);
      const unsigned int u = *(const unsigned int*)(xw + (long long)p.x * 128 + c);
      a0.x = fmaf(nm, __uint_as_float(u << 16), a0.x);
      a0.y = fmaf(nm, __uint_as_float(u & 0xffff0000u), a0.y);
    }
    float2 acc;
    acc.x = (a0.x + a1.x) + (a2.x + a3.x);
    acc.y = (a0.y + a1.y) + (a2.y + a3.y);
    const float di = dis[node];
    const float dsq = di * di;
    const unsigned int su = *(const unsigned int*)(xw + (long long)node * 128 + c);
    const float2 bv = *(const float2*)(bias + c);
    acc.x = fmaf(dsq, __uint_as_float(su << 16), acc.x) + bv.x;
    acc.y = fmaf(dsq, __uint_as_float(su & 0xffff0000u), acc.y) + bv.y;
    if (RELU) { acc.x = fmaxf(acc.x, 0.f); acc.y = fmaxf(acc.y, 0.f); }
    if (OUTBF) {
      const unsigned int pk =
          (unsigned int)f2bf(acc.x) | ((unsigned int)f2bf(acc.y) << 16);
      ((unsigned int*)outp)[(long long)node * 64 + lane] = pk;
    } else {
      *(float2*)((float*)outp + (long long)node * 128 + c) = acc;
    }
  } else {
    float a0 = 0.f, a1 = 0.f, a2 = 0.f, a3 = 0.f;
    int e = beg;
    for (; e + 3 < end; e += 4) {
      const int2 p0 = csr[e + 0];
      const int2 p1 = csr[e + 1];
      const int2 p2 = csr[e + 2];
      const int2 p3 = csr[e + 3];
      const unsigned int v0 = xw[(long long)p0.x * 64 + lane];
      const unsigned int v1 = xw[(long long)p1.x * 64 + lane];
      const unsigned int v2 = xw[(long long)p2.x * 64 + lane];
      const unsigned int v3 = xw[(long long)p3.x * 64 + lane];
      a0 = fmaf(__int_as_float(p0.y), __uint_as_float(v0 << 16), a0);
      a1 = fmaf(__int_as_float(p1.y), __uint_as_float(v1 << 16), a1);
      a2 = fmaf(__int_as_float(p2.y), __uint_as_float(v2 << 16), a2);
      a3 = fmaf(__int_as_float(p3.y), __uint_as_float(v3 << 16), a3);
    }
    for (; e < end; ++e) {
      const int2 p = csr[e];
      const unsigned int v = xw[(long long)p.x * 64 + lane];
      a0 = fmaf(__int_as_float(p.y), __uint_as_float(v << 16), a0);
    }
    float acc = (a0 + a1) + (a2 + a3);
    const float di = dis[node];
    const unsigned int sv = xw[(long long)node * 64 + lane];
    float r = fmaf(di * di, __uint_as_float(sv << 16), acc) + bias[lane];
    if (RELU) r = fmaxf(r, 0.f);
    ((float*)outp)[(long long)node * 64 + lane] = r;
  }
}

extern "C" void kernel_launch(void* const* d_in, const int* in_sizes, int n_in,
                              void* d_out, int out_size, void* d_ws, size_t ws_size,
                              hipStream_t stream) {
  const float* x  = (const float*)d_in[0];
  const int*   ei = (const int*)d_in[1];
  const float* ew = (const float*)d_in[2];
  const float* W1 = (const float*)d_in[3];
  const float* b1 = (const float*)d_in[4];
  const float* W2 = (const float*)d_in[5];
  const float* b2 = (const float*)d_in[6];
  const float* W3 = (const float*)d_in[7];
  const float* b3 = (const float*)d_in[8];
  float* out = (float*)d_out;

  const int IN = 128, HID = 128;
  const int N = in_sizes[0] / IN;   // 100000
  const int E = in_sizes[2];        // 1600000

  char* ws = (char*)d_ws;
  unsigned long long* packed = (unsigned long long*)(ws);
  float* dis       = (float*)(ws + (1u << 20));
  int*   flag      = (int*)(ws + (1536u << 10));
  int*   bsums     = (int*)(ws + (1536u << 10) + 4096);
  int*   row_start = (int*)(ws + (1600u << 10));
  int2*  csr       = (int2*)(ws + (2560u << 10));
  unsigned short* Wt1 = (unsigned short*)(ws + (15872u << 10));
  unsigned short* Wt2 = (unsigned short*)(ws + (15872u << 10) + (128u << 10));
  unsigned short* Wt3 = (unsigned short*)(ws + (15872u << 10) + (256u << 10));
  unsigned short* bufA = (unsigned short*)(ws + (16u << 20));   // bf16 xw
  unsigned short* hbf  = (unsigned short*)(ws + (42u << 20));   // bf16 x / h
  int* eseq = (int*)bufA;   // dead before GEMM1 writes bufA

  const dim3 blk(256);
  const int gE = (E + 255) / 256;
  const int gN = (N + 255) / 256;
  const int B = (N + 1023) / 1024;

  // --- CSR build + normalization coefficients ---
  hipLaunchKernelGGL(detect_i64, dim3(1), blk, 0, stream, ei, flag);
  hipLaunchKernelGGL(zero_ints, dim3(128), blk, 0, stream, (int*)packed, 2 * N);
  hipLaunchKernelGGL(count_deg_pack, dim3(gE), blk, 0, stream, ei, flag, ew, packed, eseq, E);
  hipLaunchKernelGGL(scan_phase1, dim3(B), blk, 0, stream, packed, bsums, N);
  hipLaunchKernelGGL(scan_phase2, dim3(1), dim3(1024), 0, stream, bsums, row_start, B, N);
  hipLaunchKernelGGL(scan_phase3, dim3(B), blk, 0, stream, packed, bsums, row_start, N);
  hipLaunchKernelGGL(dis_kernel, dim3(gN), blk, 0, stream, packed, dis, N);
  hipLaunchKernelGGL(fill_csr, dim3(gE), blk, 0, stream, ei, flag, ew, dis, row_start, eseq, csr, E);

  // --- weight transpose+convert, x convert ---
  hipLaunchKernelGGL(wt_bf16, dim3((128 * 128 + 255) / 256), blk, 0, stream, W1, Wt1, 128);
  hipLaunchKernelGGL(wt_bf16, dim3((128 * 128 + 255) / 256), blk, 0, stream, W2, Wt2, 128);
  hipLaunchKernelGGL(wt_bf16, dim3((64 * 128 + 255) / 256), blk, 0, stream, W3, Wt3, 64);
  hipLaunchKernelGGL(conv_bf16, dim3(1024), blk, 0, stream, x, hbf, (long long)N * 32);

  const int gGemm = (N + 63) / 64;
  const int gGather = (N + 3) / 4;

  // --- layer 1 ---
  hipLaunchKernelGGL((gemm_mfma<128>), dim3(gGemm), blk, 0, stream, hbf, Wt1, bufA, N);
  hipLaunchKernelGGL((gather<128, true, true>), dim3(gGather), blk, 0, stream,
                     csr, row_start, bufA, dis, b1, hbf, N);
  // --- layer 2 ---
  hipLaunchKernelGGL((gemm_mfma<128>), dim3(gGemm), blk, 0, stream, hbf, Wt2, bufA, N);
  hipLaunchKernelGGL((gather<128, true, true>), dim3(gGather), blk, 0, stream,
                     csr, row_start, bufA, dis, b2, hbf, N);
  // --- layer 3 ---
  hipLaunchKernelGGL((gemm_mfma<64>), dim3(gGemm), blk, 0, stream, hbf, Wt3, bufA, N);
  hipLaunchKernelGGL((gather<64, false, false>), dim3(gGather), blk, 0, stream,
                     csr, row_start, bufA, dis, b3, out, N);
}

// Round 7
// 487.713 us; speedup vs baseline: 4.2385x; 1.1459x over previous
//
#include <hip/hip_runtime.h>

// ---------------------------------------------------------------------------
// GCN 3-layer forward. CSR-gather (unroll-8, scalar CSR reads) + bf16 MFMA GEMM.
// d_ws layout (max ~67.6 MB used; 119.2 MB proven safe):
//   [0)      packed: N u64 {hi=count, lo=fixed24 sum(ew)}   (800 KB)
//   [1 MB)   dis: N floats
//   [1.5 MB) flag: 1 int;  [1.5MB+4K) bsums: up to 1024 ints
//   [1.6 MB) row_start: (N+1) ints
//   [2.5 MB) csr: E x int2 {src, norm-as-int}  (12.8 MB, ends 15.3 MB)
//   [15.5MB) Wt1 bf16 [128][128]; Wt2; Wt3 [64][128]
//   [16 MB)  bufA: N*128 bf16 xw (25.6 MB; eseq E ints aliases its head)
//   [42 MB)  hbf: N*128 bf16 (x_bf16, then h1_bf16, then h2_bf16)
// ---------------------------------------------------------------------------

typedef __attribute__((ext_vector_type(8))) short bf16x8;
typedef __attribute__((ext_vector_type(4))) float f32x4;

__device__ inline unsigned short f2bf(float f) {   // RNE f32 -> bf16
  unsigned int u = __float_as_uint(f);
  u += 0x7fffu + ((u >> 16) & 1u);
  return (unsigned short)(u >> 16);
}

// Block 0: detect int64 edge layout. All blocks: grid-stride zero of packed.
__global__ void init_kernel(const int* __restrict__ ei, int* __restrict__ flag,
                            int* __restrict__ pz, int n) {
  if (blockIdx.x == 0) {
    __shared__ int nonzero;
    if (threadIdx.x == 0) nonzero = 0;
    __syncthreads();
    int acc = 0;
#pragma unroll
    for (int it = 0; it < 8; ++it) {
      const int j = threadIdx.x + (it << 8);
      acc |= ei[2 * j + 1];
    }
    if (acc != 0) atomicOr(&nonzero, 1);
    __syncthreads();
    if (threadIdx.x == 0) flag[0] = (nonzero == 0) ? 1 : 0;
  }
  int i = blockIdx.x * blockDim.x + threadIdx.x;
  const int stride = gridDim.x * blockDim.x;
  for (; i < n; i += stride) pz[i] = 0;
}

// One packed u64 atomic per edge: hi += 1 (count), lo += ew * 2^24 (deg).
__global__ void count_deg_pack(const int* __restrict__ ei, const int* __restrict__ flag,
                               const float* __restrict__ ew,
                               unsigned long long* __restrict__ packed,
                               int* __restrict__ eseq, int E) {
  const int e = blockIdx.x * blockDim.x + threadIdx.x;
  if (e >= E) return;
  const int use64 = flag[0];
  const int d = use64 ? ei[2 * (E + e)] : ei[E + e];
  const unsigned int fx = (unsigned int)(ew[e] * 16777216.0f);  // 2^24 fixed point
  const unsigned long long old =
      atomicAdd(&packed[d], (1ULL << 32) | (unsigned long long)fx);
  eseq[e] = (int)(old >> 32);
}

// ---- 3-phase device-wide exclusive scan over hi words ----
__global__ __launch_bounds__(256)
void scan_phase1(const unsigned long long* __restrict__ packed,
                 int* __restrict__ bsums, int N) {
  __shared__ int red[256];
  const int t = threadIdx.x;
  const int base = blockIdx.x * 1024 + t * 4;
  int s = 0;
#pragma unroll
  for (int j = 0; j < 4; ++j) {
    const int idx = base + j;
    if (idx < N) s += (int)(packed[idx] >> 32);
  }
  red[t] = s;
  __syncthreads();
  for (int off = 128; off > 0; off >>= 1) {
    if (t < off) red[t] += red[t + off];
    __syncthreads();
  }
  if (t == 0) bsums[blockIdx.x] = red[0];
}

__global__ __launch_bounds__(1024)
void scan_phase2(int* __restrict__ bsums, int* __restrict__ row_start, int B, int N) {
  __shared__ int s[1024];
  const int t = threadIdx.x;
  const int v = (t < B) ? bsums[t] : 0;
  s[t] = v;
  __syncthreads();
  for (int off = 1; off < 1024; off <<= 1) {
    const int add = (t >= off) ? s[t - off] : 0;
    __syncthreads();
    s[t] += add;
    __syncthreads();
  }
  if (t < B) bsums[t] = s[t] - v;
  if (t == B - 1) row_start[N] = s[t];
}

// Phase 3 + dis = rsqrt(deg+1) fused (same index space, packed already in hand).
__global__ __launch_bounds__(256)
void scan_phase3_dis(const unsigned long long* __restrict__ packed,
                     const int* __restrict__ bsums, int* __restrict__ row_start,
                     float* __restrict__ dis, int N) {
  __shared__ int tsum[256];
  const int t = threadIdx.x;
  const int base = blockIdx.x * 1024 + t * 4;
  unsigned long long pk[4];
  int v[4];
#pragma unroll
  for (int j = 0; j < 4; ++j) {
    pk[j] = (base + j < N) ? packed[base + j] : 0ULL;
    v[j] = (int)(pk[j] >> 32);
  }
  const int tot = v[0] + v[1] + v[2] + v[3];
  tsum[t] = tot;
  __syncthreads();
  for (int off = 1; off < 256; off <<= 1) {
    const int add = (t >= off) ? tsum[t - off] : 0;
    __syncthreads();
    tsum[t] += add;
    __syncthreads();
  }
  int run = bsums[blockIdx.x] + tsum[t] - tot;
#pragma unroll
  for (int j = 0; j < 4; ++j) {
    const int idx = base + j;
    if (idx < N) {
      row_start[idx] = run;
      run += v[j];
      const float deg = (float)(unsigned int)pk[j] * (1.0f / 16777216.0f);
      dis[idx] = rsqrtf(deg + 1.0f);
    }
  }
}

// csr[row_start[dst] + eseq[e]] = {src, norm}.  No atomics.
__global__ void fill_csr(const int* __restrict__ ei, const int* __restrict__ flag,
                         const float* __restrict__ ew, const float* __restrict__ dis,
                         const int* __restrict__ row_start, const int* __restrict__ eseq,
                         int2* __restrict__ csr, int E) {
  const int e = blockIdx.x * blockDim.x + threadIdx.x;
  if (e >= E) return;
  const int use64 = flag[0];
  const int s = use64 ? ei[2 * e] : ei[e];
  const int d = use64 ? ei[2 * (E + e)] : ei[E + e];
  const float nm = dis[s] * ew[e] * dis[d];
  const int pos = row_start[d] + eseq[e];
  csr[pos] = make_int2(s, __float_as_int(nm));
}

// Fused operand prep: blocks [0,160) transpose+convert W1/W2/W3; rest convert x.
__global__ __launch_bounds__(256)
void prep_bf16(const float* __restrict__ W1, const float* __restrict__ W2,
               const float* __restrict__ W3, unsigned short* __restrict__ Wt1,
               unsigned short* __restrict__ Wt2, unsigned short* __restrict__ Wt3,
               const float* __restrict__ x, unsigned short* __restrict__ xbf,
               long long n4) {
  const int WTB = 160;  // 160*256 = 40960 = 16384+16384+8192 weight elems
  if (blockIdx.x < WTB) {
    const int idx = blockIdx.x * 256 + threadIdx.x;
    if (idx < 16384) {
      const int m = idx >> 7, k = idx & 127;
      Wt1[idx] = f2bf(W1[k * 128 + m]);
    } else if (idx < 32768) {
      const int l = idx - 16384;
      const int m = l >> 7, k = l & 127;
      Wt2[l] = f2bf(W2[k * 128 + m]);
    } else {
      const int l = idx - 32768;
      const int m = l >> 7, k = l & 127;
      Wt3[l] = f2bf(W3[k * 64 + m]);
    }
    return;
  }
  long long i = (long long)(blockIdx.x - WTB) * 256 + threadIdx.x;
  const long long stride = (long long)(gridDim.x - WTB) * 256;
  for (; i < n4; i += stride) {
    const float4 v = ((const float4*)x)[i];
    ushort4 o;
    o.x = f2bf(v.x); o.y = f2bf(v.y); o.z = f2bf(v.z); o.w = f2bf(v.w);
    ((ushort4*)xbf)[i] = o;
  }
}

// C[N x M] = A[N x 128] @ B[128 x M] via 16x16x32 bf16 MFMA, LDS-free.
template <int M>
__global__ __launch_bounds__(256)
void gemm_mfma(const unsigned short* __restrict__ A, const unsigned short* __restrict__ Bt,
               unsigned short* __restrict__ C, int N) {
  const int lane = threadIdx.x & 63;
  const int m = lane & 15;
  const int q = lane >> 4;
  const int row0 = (blockIdx.x << 6) + ((threadIdx.x >> 6) << 4);

  const bool rowok = (row0 + m) < N;
  const unsigned short* arow = A + (long long)(row0 + m) * 128 + q * 8;
  bf16x8 a[4];
  const bf16x8 zf = {0, 0, 0, 0, 0, 0, 0, 0};
#pragma unroll
  for (int kt = 0; kt < 4; ++kt)
    a[kt] = rowok ? *(const bf16x8*)(arow + kt * 32) : zf;

#pragma unroll
  for (int ct = 0; ct < M / 16; ++ct) {
    f32x4 acc = {0.f, 0.f, 0.f, 0.f};
    const unsigned short* brow = Bt + (ct * 16 + m) * 128 + q * 8;
#pragma unroll
    for (int kt = 0; kt < 4; ++kt) {
      const bf16x8 b = *(const bf16x8*)(brow + kt * 32);
      acc = __builtin_amdgcn_mfma_f32_16x16x32_bf16(a[kt], b, acc, 0, 0, 0);
    }
#pragma unroll
    for (int r = 0; r < 4; ++r) {
      const int row = row0 + q * 4 + r;
      if (row < N) C[(long long)row * M + ct * 16 + m] = f2bf(acc[r]);
    }
  }
}

// One wave per dst node, 8-way edge unroll, wave-uniform (scalar) CSR reads.
template <int M, bool RELU, bool OUTBF>
__global__ __launch_bounds__(256)
void gather(const int2* __restrict__ csr, const int* __restrict__ row_start,
            const unsigned short* __restrict__ xw, const float* __restrict__ dis,
            const float* __restrict__ bias, void* __restrict__ outp, int N) {
  const int node = (blockIdx.x << 2) + (threadIdx.x >> 6);
  const int lane = threadIdx.x & 63;
  if (node >= N) return;
  const int beg = __builtin_amdgcn_readfirstlane(row_start[node]);
  const int end = __builtin_amdgcn_readfirstlane(row_start[node + 1]);
  if (M == 128) {
    const int c = lane << 1;
    float2 a0 = make_float2(0.f, 0.f), a1 = a0, a2 = a0, a3 = a0;
    int e = beg;
    for (; e + 7 < end; e += 8) {
      int2 p[8];
      unsigned int u[8];
#pragma unroll
      for (int j = 0; j < 8; ++j) p[j] = csr[e + j];
#pragma unroll
      for (int j = 0; j < 8; ++j)
        u[j] = *(const unsigned int*)(xw + (long long)p[j].x * 128 + c);
#pragma unroll
      for (int j = 0; j < 8; ++j) {
        const float nm = __int_as_float(p[j].y);
        float2& ac = (j & 4) ? ((j & 2) ? a3 : a2) : ((j & 2) ? a1 : a0);
        ac.x = fmaf(nm, __uint_as_float(u[j] << 16), ac.x);
        ac.y = fmaf(nm, __uint_as_float(u[j] & 0xffff0000u), ac.y);
      }
    }
    for (; e + 1 < end; e += 2) {
      const int2 p0 = csr[e], p1 = csr[e + 1];
      const unsigned int u0 = *(const unsigned int*)(xw + (long long)p0.x * 128 + c);
      const unsigned int u1 = *(const unsigned int*)(xw + (long long)p1.x * 128 + c);
      const float n0 = __int_as_float(p0.y), n1 = __int_as_float(p1.y);
      a0.x = fmaf(n0, __uint_as_float(u0 << 16), a0.x);
      a0.y = fmaf(n0, __uint_as_float(u0 & 0xffff0000u), a0.y);
      a1.x = fmaf(n1, __uint_as_float(u1 << 16), a1.x);
      a1.y = fmaf(n1, __uint_as_float(u1 & 0xffff0000u), a1.y);
    }
    if (e < end) {
      const int2 p = csr[e];
      const float nm = __int_as_float(p.y);
      const unsigned int u = *(const unsigned int*)(xw + (long long)p.x * 128 + c);
      a2.x = fmaf(nm, __uint_as_float(u << 16), a2.x);
      a2.y = fmaf(nm, __uint_as_float(u & 0xffff0000u), a2.y);
    }
    float2 acc;
    acc.x = (a0.x + a1.x) + (a2.x + a3.x);
    acc.y = (a0.y + a1.y) + (a2.y + a3.y);
    const float di = dis[node];
    const float dsq = di * di;
    const unsigned int su = *(const unsigned int*)(xw + (long long)node * 128 + c);
    const float2 bv = *(const float2*)(bias + c);
    acc.x = fmaf(dsq, __uint_as_float(su << 16), acc.x) + bv.x;
    acc.y = fmaf(dsq, __uint_as_float(su & 0xffff0000u), acc.y) + bv.y;
    if (RELU) { acc.x = fmaxf(acc.x, 0.f); acc.y = fmaxf(acc.y, 0.f); }
    if (OUTBF) {
      const unsigned int pk =
          (unsigned int)f2bf(acc.x) | ((unsigned int)f2bf(acc.y) << 16);
      ((unsigned int*)outp)[(long long)node * 64 + lane] = pk;
    } else {
      *(float2*)((float*)outp + (long long)node * 128 + c) = acc;
    }
  } else {
    float a0 = 0.f, a1 = 0.f, a2 = 0.f, a3 = 0.f;
    int e = beg;
    for (; e + 7 < end; e += 8) {
      int2 p[8];
      unsigned int v[8];
#pragma unroll
      for (int j = 0; j < 8; ++j) p[j] = csr[e + j];
#pragma unroll
      for (int j = 0; j < 8; ++j) v[j] = xw[(long long)p[j].x * 64 + lane];
#pragma unroll
      for (int j = 0; j < 8; ++j) {
        float& ac = (j & 4) ? ((j & 2) ? a3 : a2) : ((j & 2) ? a1 : a0);
        ac = fmaf(__int_as_float(p[j].y), __uint_as_float(v[j] << 16), ac);
      }
    }
    for (; e < end; ++e) {
      const int2 p = csr[e];
      const unsigned int v = xw[(long long)p.x * 64 + lane];
      a0 = fmaf(__int_as_float(p.y), __uint_as_float(v << 16), a0);
    }
    float acc = (a0 + a1) + (a2 + a3);
    const float di = dis[node];
    const unsigned int sv = xw[(long long)node * 64 + lane];
    float r = fmaf(di * di, __uint_as_float(sv << 16), acc) + bias[lane];
    if (RELU) r = fmaxf(r, 0.f);
    ((float*)outp)[(long long)node * 64 + lane] = r;
  }
}

extern "C" void kernel_launch(void* const* d_in, const int* in_sizes, int n_in,
                              void* d_out, int out_size, void* d_ws, size_t ws_size,
                              hipStream_t stream) {
  const float* x  = (const float*)d_in[0];
  const int*   ei = (const int*)d_in[1];
  const float* ew = (const float*)d_in[2];
  const float* W1 = (const float*)d_in[3];
  const float* b1 = (const float*)d_in[4];
  const float* W2 = (const float*)d_in[5];
  const float* b2 = (const float*)d_in[6];
  const float* W3 = (const float*)d_in[7];
  const float* b3 = (const float*)d_in[8];
  float* out = (float*)d_out;

  const int IN = 128;
  const int N = in_sizes[0] / IN;   // 100000
  const int E = in_sizes[2];        // 1600000

  char* ws = (char*)d_ws;
  unsigned long long* packed = (unsigned long long*)(ws);
  float* dis       = (float*)(ws + (1u << 20));
  int*   flag      = (int*)(ws + (1536u << 10));
  int*   bsums     = (int*)(ws + (1536u << 10) + 4096);
  int*   row_start = (int*)(ws + (1600u << 10));
  int2*  csr       = (int2*)(ws + (2560u << 10));
  unsigned short* Wt1 = (unsigned short*)(ws + (15872u << 10));
  unsigned short* Wt2 = (unsigned short*)(ws + (15872u << 10) + (128u << 10));
  unsigned short* Wt3 = (unsigned short*)(ws + (15872u << 10) + (256u << 10));
  unsigned short* bufA = (unsigned short*)(ws + (16u << 20));   // bf16 xw
  unsigned short* hbf  = (unsigned short*)(ws + (42u << 20));   // bf16 x / h
  int* eseq = (int*)bufA;   // dead before GEMM1 writes bufA

  const dim3 blk(256);
  const int gE = (E + 255) / 256;
  const int B = (N + 1023) / 1024;

  // --- CSR build + normalization coefficients (7 kernels) ---
  hipLaunchKernelGGL(init_kernel, dim3(128), blk, 0, stream, ei, flag, (int*)packed, 2 * N);
  hipLaunchKernelGGL(count_deg_pack, dim3(gE), blk, 0, stream, ei, flag, ew, packed, eseq, E);
  hipLaunchKernelGGL(scan_phase1, dim3(B), blk, 0, stream, packed, bsums, N);
  hipLaunchKernelGGL(scan_phase2, dim3(1), dim3(1024), 0, stream, bsums, row_start, B, N);
  hipLaunchKernelGGL(scan_phase3_dis, dim3(B), blk, 0, stream, packed, bsums, row_start, dis, N);
  hipLaunchKernelGGL(fill_csr, dim3(gE), blk, 0, stream, ei, flag, ew, dis, row_start, eseq, csr, E);
  hipLaunchKernelGGL(prep_bf16, dim3(160 + 2048), blk, 0, stream,
                     W1, W2, W3, Wt1, Wt2, Wt3, x, hbf, (long long)N * 32);

  const int gGemm = (N + 63) / 64;
  const int gGather = (N + 3) / 4;

  // --- layer 1 ---
  hipLaunchKernelGGL((gemm_mfma<128>), dim3(gGemm), blk, 0, stream, hbf, Wt1, bufA, N);
  hipLaunchKernelGGL((gather<128, true, true>), dim3(gGather), blk, 0, stream,
                     csr, row_start, bufA, dis, b1, hbf, N);
  // --- layer 2 ---
  hipLaunchKernelGGL((gemm_mfma<128>), dim3(gGemm), blk, 0, stream, hbf, Wt2, bufA, N);
  hipLaunchKernelGGL((gather<128, true, true>), dim3(gGather), blk, 0, stream,
                     csr, row_start, bufA, dis, b2, hbf, N);
  // --- layer 3 ---
  hipLaunchKernelGGL((gemm_mfma<64>), dim3(gGemm), blk, 0, stream, hbf, Wt3, bufA, N);
  hipLaunchKernelGGL((gather<64, false, false>), dim3(gGather), blk, 0, stream,
                     csr, row_start, bufA, dis, b3, out, N);
}